// Round 3
// baseline (4035.649 us; speedup 1.0000x reference)
//
#include <hip/hip_runtime.h>
#include <math.h>

#define H 128
#define NTX 150000
#define NCU 40000
#define NME 10000
#define NEDGE 150000
#define NLAY 2
#define WC_STRIDE 33280     // per (l,r): QWc@0, WVc@16384, qbc@32768, bvc@32896, gvec@33024, gsc@33152
#define WKC_STRIDE 16640    // per (l,r): WKc@0, bkc@16384
#define EDGEBUF_FLOATS 19200000   // NTX*H
#define AGG2_OFF 12800000         // edgebuf offset for agg[2] (NME*H = 1.28M)
#define AGG1_OFF 14080000         // edgebuf offset for agg[1] (NCU*H = 5.12M)

__device__ __forceinline__ float gelu_exact(float x) {
    return 0.5f * x * (1.0f + erff(x * 0.70710678118654752f));
}

// ---------- fills ----------
__global__ __launch_bounds__(256) void fill0(float4* p, int n4) {
    int i = blockIdx.x * 256 + threadIdx.x;
    if (i < n4) p[i] = make_float4(0.f, 0.f, 0.f, 0.f);
}
__global__ __launch_bounds__(256) void fill_val(float* p, int n, float v) {
    int i = blockIdx.x * 256 + threadIdx.x;
    if (i < n) p[i] = v;
}

// ---------- small projection: Y = X(NxK) @ W(KxH) + b ----------
template<int K>
__global__ __launch_bounds__(256) void proj_kernel(const float* __restrict__ X,
    const float* __restrict__ W, const float* __restrict__ B,
    float* __restrict__ Y, int N)
{
    int c = threadIdx.x & 127;
    int nl = threadIdx.x >> 7;
    int n = blockIdx.x * 2 + nl;
    if (n >= N) return;
    const float* xr = X + (size_t)n * K;
    float acc = B[c];
    #pragma unroll
    for (int k = 0; k < K; ++k) acc += xr[k] * W[k * H + c];
    Y[(size_t)n * H + c] = acc;
}

// ---------- gather rows ----------
__global__ __launch_bounds__(256) void gather_rows(const float* __restrict__ src,
    const int* __restrict__ ids, float* __restrict__ dstp, int N)
{
    int t = blockIdx.x * 256 + threadIdx.x;
    if (t >= N * 32) return;
    int n = t >> 5, c4 = t & 31;
    int sid = ids[n];
    ((float4*)dstp)[(size_t)n * 32 + c4] = ((const float4*)src)[(size_t)sid * 32 + c4];
}

// ---------- combine stage 1: WKc = kw[st]@a_rel, WVc = vw[st]@m_rel (+bias rows) ----------
__global__ __launch_bounds__(256) void combine1(const float* __restrict__ kw,
    const float* __restrict__ kb, const float* __restrict__ vw, const float* __restrict__ vb,
    const float* __restrict__ a_rel, const float* __restrict__ m_rel,
    float* __restrict__ wkc, float* __restrict__ wc)
{
    __shared__ float Bs[64][128];
    int combo = blockIdx.x;           // l*4 + r
    int l = combo >> 2, r = combo & 3;
    const int src_t[4] = {1, 2, 0, 0};
    int st = src_t[r];
    const float* Ak  = kw + (size_t)(l*3 + st) * H * H;
    const float* Akb = kb + (size_t)(l*3 + st) * H;
    const float* Av  = vw + (size_t)(l*3 + st) * H * H;
    const float* Avb = vb + (size_t)(l*3 + st) * H;
    const float* Rk = a_rel + (size_t)combo * H * H;
    const float* Rv = m_rel + (size_t)combo * H * H;
    float* WKc = wkc + (size_t)combo * WKC_STRIDE;
    float* bkc = WKc + H * H;
    float* WVc = wc + (size_t)combo * WC_STRIDE + 16384;
    float* bvc = wc + (size_t)combo * WC_STRIDE + 32896;

    int tid = threadIdx.x;
    int i = tid >> 1, j0 = (tid & 1) * 64;
    for (int pass = 0; pass < 2; ++pass) {
        const float* Ap = pass ? Av : Ak;
        const float* Rp = pass ? Rv : Rk;
        float* Out = pass ? WVc : WKc;
        float acc[64];
        #pragma unroll
        for (int j = 0; j < 64; ++j) acc[j] = 0.f;
        for (int half = 0; half < 2; ++half) {
            __syncthreads();
            for (int idx = tid; idx < 64 * 128; idx += 256)
                Bs[idx >> 7][idx & 127] = Rp[(half * 64 + (idx >> 7)) * H + (idx & 127)];
            __syncthreads();
            for (int k = 0; k < 64; ++k) {
                float a = Ap[i * H + half * 64 + k];
                #pragma unroll
                for (int j = 0; j < 64; ++j) acc[j] += a * Bs[k][j0 + j];
            }
        }
        for (int j = 0; j < 64; ++j) Out[i * H + j0 + j] = acc[j];
        __syncthreads();
    }
    if (tid < 128) {
        float s1 = 0.f, s2 = 0.f;
        for (int k = 0; k < H; ++k) {
            s1 += Akb[k] * Rk[k * H + tid];
            s2 += Avb[k] * Rv[k * H + tid];
        }
        bkc[tid] = s1; bvc[tid] = s2;
    }
}

// ---------- combine stage 2: QWc = qw[dt] @ WKc^T, qbc = qb@WKc^T, gvec = qw@bkc, gsc = qb.bkc ----------
__global__ __launch_bounds__(256) void combine2(const float* __restrict__ qw,
    const float* __restrict__ qb, const float* __restrict__ wkc, float* __restrict__ wc)
{
    __shared__ float BsT[64][128];    // BsT[k][j] = WKc[j][half*64+k]
    int combo = blockIdx.x;
    int l = combo >> 2, r = combo & 3;
    const int dst_t[4] = {0, 0, 1, 2};
    int dt = dst_t[r];
    const float* Q  = qw + (size_t)(l*3 + dt) * H * H;
    const float* Qb = qb + (size_t)(l*3 + dt) * H;
    const float* WKc = wkc + (size_t)combo * WKC_STRIDE;
    const float* bkc = WKc + H * H;
    float* QWc  = wc + (size_t)combo * WC_STRIDE;
    float* qbc  = wc + (size_t)combo * WC_STRIDE + 32768;
    float* gvec = wc + (size_t)combo * WC_STRIDE + 33024;
    float* gsc  = wc + (size_t)combo * WC_STRIDE + 33152;

    int tid = threadIdx.x;
    int i = tid >> 1, j0 = (tid & 1) * 64;
    float acc[64];
    #pragma unroll
    for (int j = 0; j < 64; ++j) acc[j] = 0.f;
    for (int half = 0; half < 2; ++half) {
        __syncthreads();
        for (int idx = tid; idx < 64 * 128; idx += 256) {
            int k = idx & 63, j = idx >> 6;
            BsT[k][j] = WKc[j * H + half * 64 + k];
        }
        __syncthreads();
        for (int k = 0; k < 64; ++k) {
            float a = Q[i * H + half * 64 + k];
            #pragma unroll
            for (int j = 0; j < 64; ++j) acc[j] += a * BsT[k][j0 + j];
        }
    }
    for (int j = 0; j < 64; ++j) QWc[i * H + j0 + j] = acc[j];
    if (tid < 128) {
        float s = 0.f, g = 0.f;
        for (int k = 0; k < H; ++k) {
            s += Qb[k] * WKc[tid * H + k];
            g += Q[tid * H + k] * bkc[k];
        }
        qbc[tid] = s; gvec[tid] = g;
    }
    if (tid == 0) {
        float s = 0.f;
        for (int k = 0; k < H; ++k) s += Qb[k] * bkc[k];
        gsc[0] = s;
    }
}

// ---------- node GEMM: 64 rows x 128 cols per block ----------
// MODE 0: Y = X@W + B
// MODE 1: Y = relu(beta*(gelu(X)@W + B) + (1-beta)*Xold)
// MODE 2: Y += X@W + (zb[n]>0)*B       (accumulate)
template<int MODE>
__global__ __launch_bounds__(256) void node_gemm(const float* __restrict__ X,
    const float* __restrict__ W, const float* __restrict__ B, float* __restrict__ Y,
    int N, const float* __restrict__ Xold, const float* __restrict__ skipP,
    const float* __restrict__ zb)
{
    __shared__ float xs[64][132];
    int nb = blockIdx.x * 64;
    int tid = threadIdx.x;

    #pragma unroll
    for (int i = 0; i < 8; ++i) {
        int u = tid + i * 256;
        int n = u >> 5, c4 = u & 31;
        int gn = nb + n;
        float4 v = make_float4(0.f, 0.f, 0.f, 0.f);
        if (gn < N) v = *(const float4*)(X + (size_t)gn * H + c4 * 4);
        if (MODE == 1) {
            v.x = gelu_exact(v.x); v.y = gelu_exact(v.y);
            v.z = gelu_exact(v.z); v.w = gelu_exact(v.w);
        }
        xs[n][c4*4 + 0] = v.x; xs[n][c4*4 + 1] = v.y;
        xs[n][c4*4 + 2] = v.z; xs[n][c4*4 + 3] = v.w;
    }
    __syncthreads();

    int cq = tid & 15;
    int ng = tid >> 4;
    int c0 = cq * 8;
    float4 a0[4], a1[4];
    #pragma unroll
    for (int j = 0; j < 4; ++j) {
        a0[j] = make_float4(0.f,0.f,0.f,0.f);
        a1[j] = make_float4(0.f,0.f,0.f,0.f);
    }

    for (int k = 0; k < H; k += 4) {
        float xr[4][4];
        #pragma unroll
        for (int j = 0; j < 4; ++j)
            *(float4*)(&xr[j][0]) = *(const float4*)(&xs[ng*4 + j][k]);
        #pragma unroll
        for (int kk = 0; kk < 4; ++kk) {
            float4 w0 = *(const float4*)(W + (size_t)(k + kk) * H + c0);
            float4 w1 = *(const float4*)(W + (size_t)(k + kk) * H + c0 + 4);
            #pragma unroll
            for (int j = 0; j < 4; ++j) {
                float xv = xr[j][kk];
                a0[j].x += xv * w0.x; a0[j].y += xv * w0.y;
                a0[j].z += xv * w0.z; a0[j].w += xv * w0.w;
                a1[j].x += xv * w1.x; a1[j].y += xv * w1.y;
                a1[j].z += xv * w1.z; a1[j].w += xv * w1.w;
            }
        }
    }

    float4 b0 = *(const float4*)(B + c0);
    float4 b1 = *(const float4*)(B + c0 + 4);
    float beta = 0.f, omb = 0.f;
    if (MODE == 1) {
        float s = *skipP;
        beta = 1.f / (1.f + expf(-s));
        omb = 1.f - beta;
    }
    #pragma unroll
    for (int j = 0; j < 4; ++j) {
        int gn = nb + ng*4 + j;
        if (gn < N) {
            float4 r0, r1;
            r0.x = a0[j].x; r0.y = a0[j].y; r0.z = a0[j].z; r0.w = a0[j].w;
            r1.x = a1[j].x; r1.y = a1[j].y; r1.z = a1[j].z; r1.w = a1[j].w;
            if (MODE == 2) {
                float gate = (zb[gn] > 0.f) ? 1.f : 0.f;
                float4 y0 = *(const float4*)(Y + (size_t)gn * H + c0);
                float4 y1 = *(const float4*)(Y + (size_t)gn * H + c0 + 4);
                r0.x += y0.x + gate*b0.x; r0.y += y0.y + gate*b0.y;
                r0.z += y0.z + gate*b0.z; r0.w += y0.w + gate*b0.w;
                r1.x += y1.x + gate*b1.x; r1.y += y1.y + gate*b1.y;
                r1.z += y1.z + gate*b1.z; r1.w += y1.w + gate*b1.w;
            } else {
                r0.x += b0.x; r0.y += b0.y; r0.z += b0.z; r0.w += b0.w;
                r1.x += b1.x; r1.y += b1.y; r1.z += b1.z; r1.w += b1.w;
            }
            if (MODE == 1) {
                float4 o0 = *(const float4*)(Xold + (size_t)gn * H + c0);
                float4 o1 = *(const float4*)(Xold + (size_t)gn * H + c0 + 4);
                r0.x = fmaxf(beta*r0.x + omb*o0.x, 0.f);
                r0.y = fmaxf(beta*r0.y + omb*o0.y, 0.f);
                r0.z = fmaxf(beta*r0.z + omb*o0.z, 0.f);
                r0.w = fmaxf(beta*r0.w + omb*o0.w, 0.f);
                r1.x = fmaxf(beta*r1.x + omb*o1.x, 0.f);
                r1.y = fmaxf(beta*r1.y + omb*o1.y, 0.f);
                r1.z = fmaxf(beta*r1.z + omb*o1.z, 0.f);
                r1.w = fmaxf(beta*r1.w + omb*o1.w, 0.f);
            }
            *(float4*)(Y + (size_t)gn * H + c0)     = r0;
            *(float4*)(Y + (size_t)gn * H + c0 + 4) = r1;
        }
    }
}

// ---------- cvec[n] = xs[n]·gvec + gsc ----------
__global__ __launch_bounds__(256) void cvec_kernel(const float* __restrict__ X,
    const float* __restrict__ gvec, const float* __restrict__ gsc,
    float* __restrict__ cvec, int N)
{
    int t = blockIdx.x * 256 + threadIdx.x;
    int n = t >> 5, lane = t & 31;
    if (n >= N) return;
    float4 xv = *(const float4*)(X + (size_t)n * H + lane * 4);
    float4 gv = *(const float4*)(gvec + lane * 4);
    float p = xv.x*gv.x + xv.y*gv.y + xv.z*gv.z + xv.w*gv.w;
    #pragma unroll
    for (int m = 16; m >= 1; m >>= 1) p += __shfl_xor(p, m);
    if (lane == 0) cvec[n] = p + gsc[0];
}

// ---------- score: expa = exp((qt[dst]·x[src] + cvec[dst]) * scale); z[dst] += expa ----------
__global__ __launch_bounds__(256) void score_kernel(const int* __restrict__ src,
    const int* __restrict__ dst, const float* __restrict__ qt, const float* __restrict__ xsrc,
    const float* __restrict__ cvec, const float* __restrict__ prel, int ridx,
    float* __restrict__ expa, float* __restrict__ z, int E)
{
    int t = blockIdx.x * 256 + threadIdx.x;
    int e = t >> 5, lane = t & 31;
    if (e >= E) return;
    int s = src[e], d = dst[e];
    float4 qv = *(const float4*)(qt + (size_t)d * H + lane * 4);
    float4 xv = *(const float4*)(xsrc + (size_t)s * H + lane * 4);
    float p = qv.x*xv.x + qv.y*xv.y + qv.z*xv.z + qv.w*xv.w;
    #pragma unroll
    for (int m = 16; m >= 1; m >>= 1) p += __shfl_xor(p, m);
    if (lane == 0) {
        float scale = prel[ridx] * 0.08838834764831843f;   // 1/sqrt(128)
        float ev = expf((p + cvec[d]) * scale);
        expa[e] = ev;
        atomicAdd(&z[d], ev);
    }
}

// ---------- scatter: raw[dst] += (expa/(z+eps)) * x[src] ----------
__global__ __launch_bounds__(256) void scatter_kernel(const int* __restrict__ src,
    const int* __restrict__ dst, const float* __restrict__ xsrc,
    const float* __restrict__ expa, const float* __restrict__ z,
    float* __restrict__ raw, int E)
{
    int t = blockIdx.x * 256 + threadIdx.x;
    int e = t >> 5, lane = t & 31;
    if (e >= E) return;
    int s = src[e], d = dst[e];
    float w = expa[e] / (z[d] + 1e-16f);
    float4 xv = *(const float4*)(xsrc + (size_t)s * H + lane * 4);
    float* ap = raw + (size_t)d * H + lane * 4;
    atomicAdd(ap + 0, w * xv.x);
    atomicAdd(ap + 1, w * xv.y);
    atomicAdd(ap + 2, w * xv.z);
    atomicAdd(ap + 3, w * xv.w);
}

// ---------- output head ----------
__global__ __launch_bounds__(256) void out_kernel(const float* __restrict__ X,
    const float* __restrict__ Wo, const float* __restrict__ bo,
    float* __restrict__ out, int N)
{
    int t = blockIdx.x * 256 + threadIdx.x;
    int n = t >> 5, lane = t & 31;
    if (n >= N) return;
    float4 xv = *(const float4*)(X + (size_t)n * H + lane * 4);
    float xa[4]; *(float4*)xa = xv;
    float p0 = 0.f, p1 = 0.f;
    #pragma unroll
    for (int j = 0; j < 4; ++j) {
        p0 += xa[j] * Wo[(lane*4 + j)*2 + 0];
        p1 += xa[j] * Wo[(lane*4 + j)*2 + 1];
    }
    #pragma unroll
    for (int m = 16; m >= 1; m >>= 1) { p0 += __shfl_xor(p0, m); p1 += __shfl_xor(p1, m); }
    if (lane == 0) {
        out[(size_t)n*2 + 0] = p0 + bo[0];
        out[(size_t)n*2 + 1] = p1 + bo[1];
    }
}

extern "C" void kernel_launch(void* const* d_in, const int* in_sizes, int n_in,
                              void* d_out, int out_size, void* d_ws, size_t ws_size,
                              hipStream_t stream)
{
    const float* x_tx      = (const float*)d_in[0];
    const float* x_cust    = (const float*)d_in[1];
    const int*   merch_ids = (const int*)d_in[2];
    const int*   e_ct_src  = (const int*)d_in[3];
    const int*   e_ct_dst  = (const int*)d_in[4];
    const int*   e_mt_src  = (const int*)d_in[5];
    const int*   e_mt_dst  = (const int*)d_in[6];
    const float* proj_tx_w   = (const float*)d_in[7];
    const float* proj_tx_b   = (const float*)d_in[8];
    const float* proj_cust_w = (const float*)d_in[9];
    const float* proj_cust_b = (const float*)d_in[10];
    const float* merch_emb   = (const float*)d_in[11];
    const float* kw = (const float*)d_in[12];
    const float* kb = (const float*)d_in[13];
    const float* qw = (const float*)d_in[14];
    const float* qb = (const float*)d_in[15];
    const float* vw = (const float*)d_in[16];
    const float* vb = (const float*)d_in[17];
    const float* aw = (const float*)d_in[18];
    const float* ab = (const float*)d_in[19];
    const float* skip  = (const float*)d_in[20];
    const float* a_rel = (const float*)d_in[21];
    const float* m_rel = (const float*)d_in[22];
    const float* p_rel = (const float*)d_in[23];
    const float* out_w = (const float*)d_in[24];
    const float* out_b = (const float*)d_in[25];
    (void)in_sizes; (void)n_in;

    const size_t nsz[3] = {NTX, NCU, NME};

    // workspace layout (floats) — total ~247.4 MB (budget measured: 256 MiB)
    float* ws = (float*)d_ws;
    size_t off = 0;
    float* xs[3];  for (int t = 0; t < 3; ++t) { xs[t] = ws + off; off += nsz[t]*H; }
    float* agg0    = ws + off; off += (size_t)NTX * H;
    float* edgebuf = ws + off; off += EDGEBUF_FLOATS;   // qt/raw; agg1,agg2 aliased in tail
    float* cvec = ws + off; off += NTX;
    float* zbuf = ws + off; off += NTX;
    float* expa = ws + off; off += NEDGE;
    float* wc   = ws + off; off += 8 * WC_STRIDE;
    float* wkc  = ws + off; off += 8 * WKC_STRIDE;
    size_t needed_bytes = off * sizeof(float);

    float* agg[3] = { agg0, edgebuf + AGG1_OFF, edgebuf + AGG2_OFF };

    if (ws_size < needed_bytes) {
        // diagnostic: report ws_size (in MB) through the output
        fill_val<<<(out_size + 255) / 256, 256, 0, stream>>>(
            (float*)d_out, out_size, (float)(ws_size >> 20));
        return;
    }

    // precombine weights
    combine1<<<8, 256, 0, stream>>>(kw, kb, vw, vb, a_rel, m_rel, wkc, wc);
    combine2<<<8, 256, 0, stream>>>(qw, qb, wkc, wc);

    // input projections
    proj_kernel<16><<<(NTX + 1) / 2, 256, 0, stream>>>(x_tx, proj_tx_w, proj_tx_b, xs[0], NTX);
    proj_kernel<32><<<(NCU + 1) / 2, 256, 0, stream>>>(x_cust, proj_cust_w, proj_cust_b, xs[1], NCU);
    gather_rows<<<(NME * 32 + 255) / 256, 256, 0, stream>>>(merch_emb, merch_ids, xs[2], NME);

    const int src_t[4] = {1, 2, 0, 0};
    const int dst_t[4] = {0, 0, 1, 2};
    const int* esrc[4] = {e_ct_src, e_mt_src, e_ct_dst, e_mt_dst};
    const int* edst[4] = {e_ct_dst, e_mt_dst, e_ct_src, e_mt_src};

    const int egrid = (NEDGE * 32 + 255) / 256;
    const int agg0_4 = NTX * H / 4;

    for (int l = 0; l < NLAY; ++l) {
        fill0<<<(agg0_4 + 255) / 256, 256, 0, stream>>>((float4*)agg0, agg0_4);

        for (int r = 0; r < 4; ++r) {
            int st = src_t[r], dt = dst_t[r];
            int ndt = (int)nsz[dt];
            int combo = l * 4 + r;
            const float* QWc  = wc + (size_t)combo * WC_STRIDE;
            const float* WVc  = QWc + 16384;
            const float* qbc  = QWc + 32768;
            const float* bvc  = QWc + 32896;
            const float* gvec = QWc + 33024;
            const float* gsc  = QWc + 33152;

            // qt = xs[dt] @ QWc + qbc   (into edgebuf[0 : ndt*H])
            node_gemm<0><<<(ndt + 63) / 64, 256, 0, stream>>>(
                xs[dt], QWc, qbc, edgebuf, ndt, nullptr, nullptr, nullptr);
            cvec_kernel<<<(ndt * 32 + 255) / 256, 256, 0, stream>>>(
                xs[dt], gvec, gsc, cvec, ndt);
            fill0<<<(ndt / 4 + 255) / 256, 256, 0, stream>>>((float4*)zbuf, ndt / 4);
            score_kernel<<<egrid, 256, 0, stream>>>(
                esrc[r], edst[r], edgebuf, xs[st], cvec, p_rel, combo, expa, zbuf, NEDGE);
            // reuse edgebuf[0 : ndt*H] as raw scatter accumulator
            fill0<<<(ndt * 32 + 255) / 256, 256, 0, stream>>>((float4*)edgebuf, ndt * 32);
            scatter_kernel<<<egrid, 256, 0, stream>>>(
                esrc[r], edst[r], xs[st], expa, zbuf, edgebuf, NEDGE);
            // agg[dt] += raw @ WVc + (z>0)*bvc
            node_gemm<2><<<(ndt + 63) / 64, 256, 0, stream>>>(
                edgebuf, WVc, bvc, agg[dt], ndt, nullptr, nullptr, zbuf);

            // after the last full-width (tx-dst) relation has consumed edgebuf,
            // zero the aliased agg1/agg2 tail region [AGG2_OFF : EDGEBUF_FLOATS)
            if (r == 1) {
                int tail4 = (EDGEBUF_FLOATS - AGG2_OFF) / 4;
                fill0<<<(tail4 + 255) / 256, 256, 0, stream>>>(
                    (float4*)(edgebuf + AGG2_OFF), tail4);
            }
        }

        // update: xs = relu(beta*(gelu(agg)@aw + ab) + (1-beta)*xs)
        for (int t = 0; t < 3; ++t)
            node_gemm<1><<<(int)((nsz[t] + 63) / 64), 256, 0, stream>>>(
                agg[t], aw + (size_t)(l*3 + t)*H*H, ab + (size_t)(l*3 + t)*H,
                xs[t], (int)nsz[t], xs[t], skip + l*3 + t, nullptr);
    }

    out_kernel<<<(NTX * 32 + 255) / 256, 256, 0, stream>>>(xs[0], out_w, out_b, (float*)d_out, NTX);
}

// Round 4
// 2032.705 us; speedup vs baseline: 1.9854x; 1.9854x over previous
//
#include <hip/hip_runtime.h>
#include <math.h>

#define H 128
#define NTX 150000
#define NCU 40000
#define NME 10000
#define NEDGE 150000
#define NLAY 2
#define WC_STRIDE 33280     // per (l,r): QWc@0, WVc@16384, qbc@32768, bvc@32896, gvec@33024, gsc@33152
#define WKC_STRIDE 16640    // per (l,r): WKc@0, bkc@16384
#define EDGEBUF_FLOATS 19200000   // NTX*H
#define AGG2_OFF 12800000         // edgebuf offset for agg[2] (NME*H = 1.28M)
#define AGG1_OFF 14080000         // edgebuf offset for agg[1] (NCU*H = 5.12M)
#define SCAN_TILE 2048

__device__ __forceinline__ float gelu_exact(float x) {
    return 0.5f * x * (1.0f + erff(x * 0.70710678118654752f));
}

// ---------- fills ----------
__global__ __launch_bounds__(256) void fill0(float4* p, int n4) {
    int i = blockIdx.x * 256 + threadIdx.x;
    if (i < n4) p[i] = make_float4(0.f, 0.f, 0.f, 0.f);
}
__global__ __launch_bounds__(256) void fill_val(float* p, int n, float v) {
    int i = blockIdx.x * 256 + threadIdx.x;
    if (i < n) p[i] = v;
}
__global__ __launch_bounds__(256) void zero_int(int* p, int n) {
    int i = blockIdx.x * 256 + threadIdx.x;
    if (i < n) p[i] = 0;
}
__global__ __launch_bounds__(256) void copy_int(int* d, const int* s, int n) {
    int i = blockIdx.x * 256 + threadIdx.x;
    if (i < n) d[i] = s[i];
}

// ---------- CSR build ----------
__global__ __launch_bounds__(256) void count_deg(const int* __restrict__ dst,
    int* __restrict__ deg, int E)
{
    int e = blockIdx.x * 256 + threadIdx.x;
    if (e < E) atomicAdd(&deg[dst[e]], 1);
}
// scan1: per-block (2048 elems) exclusive prefix into out; block total into bsum
__global__ __launch_bounds__(256) void scan1(const int* __restrict__ deg,
    int* __restrict__ out, int* __restrict__ bsum, int n)
{
    __shared__ int ts[256];
    int tid = threadIdx.x;
    int base = blockIdx.x * SCAN_TILE + tid * 8;
    int v[8], pre[8], s = 0;
    #pragma unroll
    for (int j = 0; j < 8; ++j) {
        int idx = base + j;
        v[j] = (idx < n) ? deg[idx] : 0;
        pre[j] = s; s += v[j];
    }
    ts[tid] = s;
    __syncthreads();
    for (int off = 1; off < 256; off <<= 1) {
        int t = (tid >= off) ? ts[tid - off] : 0;
        __syncthreads();
        ts[tid] += t;
        __syncthreads();
    }
    int excl = ts[tid] - s;
    #pragma unroll
    for (int j = 0; j < 8; ++j)
        if (base + j < n) out[base + j] = excl + pre[j];
    if (tid == 255) bsum[blockIdx.x] = ts[255];
}
__global__ __launch_bounds__(64) void scan2(int* __restrict__ bsum, int nb) {
    if (threadIdx.x == 0 && blockIdx.x == 0) {
        int run = 0;
        for (int i = 0; i < nb; ++i) { int t = bsum[i]; bsum[i] = run; run += t; }
    }
}
__global__ __launch_bounds__(256) void scan3(int* __restrict__ out,
    const int* __restrict__ bsum, int n, int total)
{
    int i = blockIdx.x * 256 + threadIdx.x;
    int idx = blockIdx.x * SCAN_TILE + threadIdx.x;   // not used; keep simple below
    (void)idx; (void)i;
    int base = blockIdx.x * SCAN_TILE;
    int add = bsum[blockIdx.x];
    for (int j = threadIdx.x; j < SCAN_TILE; j += 256) {
        int k = base + j;
        if (k < n) out[k] += add;
    }
    if (blockIdx.x == 0 && threadIdx.x == 0) out[n] = total;
}
__global__ __launch_bounds__(256) void fill_csr(const int* __restrict__ src,
    const int* __restrict__ dst, int* __restrict__ cursor, int* __restrict__ col, int E)
{
    int e = blockIdx.x * 256 + threadIdx.x;
    if (e >= E) return;
    int pos = atomicAdd(&cursor[dst[e]], 1);
    col[pos] = src[e];
}

// ---------- small projection: Y = X(NxK) @ W(KxH) + b ----------
template<int K>
__global__ __launch_bounds__(256) void proj_kernel(const float* __restrict__ X,
    const float* __restrict__ W, const float* __restrict__ B,
    float* __restrict__ Y, int N)
{
    int c = threadIdx.x & 127;
    int nl = threadIdx.x >> 7;
    int n = blockIdx.x * 2 + nl;
    if (n >= N) return;
    const float* xr = X + (size_t)n * K;
    float acc = B[c];
    #pragma unroll
    for (int k = 0; k < K; ++k) acc += xr[k] * W[k * H + c];
    Y[(size_t)n * H + c] = acc;
}

// ---------- gather rows ----------
__global__ __launch_bounds__(256) void gather_rows(const float* __restrict__ src,
    const int* __restrict__ ids, float* __restrict__ dstp, int N)
{
    int t = blockIdx.x * 256 + threadIdx.x;
    if (t >= N * 32) return;
    int n = t >> 5, c4 = t & 31;
    int sid = ids[n];
    ((float4*)dstp)[(size_t)n * 32 + c4] = ((const float4*)src)[(size_t)sid * 32 + c4];
}

// ---------- combine stage 1 ----------
__global__ __launch_bounds__(256) void combine1(const float* __restrict__ kw,
    const float* __restrict__ kb, const float* __restrict__ vw, const float* __restrict__ vb,
    const float* __restrict__ a_rel, const float* __restrict__ m_rel,
    float* __restrict__ wkc, float* __restrict__ wc)
{
    __shared__ float Bs[64][128];
    int combo = blockIdx.x;           // l*4 + r
    int l = combo >> 2, r = combo & 3;
    const int src_t[4] = {1, 2, 0, 0};
    int st = src_t[r];
    const float* Ak  = kw + (size_t)(l*3 + st) * H * H;
    const float* Akb = kb + (size_t)(l*3 + st) * H;
    const float* Av  = vw + (size_t)(l*3 + st) * H * H;
    const float* Avb = vb + (size_t)(l*3 + st) * H;
    const float* Rk = a_rel + (size_t)combo * H * H;
    const float* Rv = m_rel + (size_t)combo * H * H;
    float* WKc = wkc + (size_t)combo * WKC_STRIDE;
    float* bkc = WKc + H * H;
    float* WVc = wc + (size_t)combo * WC_STRIDE + 16384;
    float* bvc = wc + (size_t)combo * WC_STRIDE + 32896;

    int tid = threadIdx.x;
    int i = tid >> 1, j0 = (tid & 1) * 64;
    for (int pass = 0; pass < 2; ++pass) {
        const float* Ap = pass ? Av : Ak;
        const float* Rp = pass ? Rv : Rk;
        float* Out = pass ? WVc : WKc;
        float acc[64];
        #pragma unroll
        for (int j = 0; j < 64; ++j) acc[j] = 0.f;
        for (int half = 0; half < 2; ++half) {
            __syncthreads();
            for (int idx = tid; idx < 64 * 128; idx += 256)
                Bs[idx >> 7][idx & 127] = Rp[(half * 64 + (idx >> 7)) * H + (idx & 127)];
            __syncthreads();
            for (int k = 0; k < 64; ++k) {
                float a = Ap[i * H + half * 64 + k];
                #pragma unroll
                for (int j = 0; j < 64; ++j) acc[j] += a * Bs[k][j0 + j];
            }
        }
        for (int j = 0; j < 64; ++j) Out[i * H + j0 + j] = acc[j];
        __syncthreads();
    }
    if (tid < 128) {
        float s1 = 0.f, s2 = 0.f;
        for (int k = 0; k < H; ++k) {
            s1 += Akb[k] * Rk[k * H + tid];
            s2 += Avb[k] * Rv[k * H + tid];
        }
        bkc[tid] = s1; bvc[tid] = s2;
    }
}

// ---------- combine stage 2 ----------
__global__ __launch_bounds__(256) void combine2(const float* __restrict__ qw,
    const float* __restrict__ qb, const float* __restrict__ wkc, float* __restrict__ wc)
{
    __shared__ float BsT[64][128];    // BsT[k][j] = WKc[j][half*64+k]
    int combo = blockIdx.x;
    int l = combo >> 2, r = combo & 3;
    const int dst_t[4] = {0, 0, 1, 2};
    int dt = dst_t[r];
    const float* Q  = qw + (size_t)(l*3 + dt) * H * H;
    const float* Qb = qb + (size_t)(l*3 + dt) * H;
    const float* WKc = wkc + (size_t)combo * WKC_STRIDE;
    const float* bkc = WKc + H * H;
    float* QWc  = wc + (size_t)combo * WC_STRIDE;
    float* qbc  = wc + (size_t)combo * WC_STRIDE + 32768;
    float* gvec = wc + (size_t)combo * WC_STRIDE + 33024;
    float* gsc  = wc + (size_t)combo * WC_STRIDE + 33152;

    int tid = threadIdx.x;
    int i = tid >> 1, j0 = (tid & 1) * 64;
    float acc[64];
    #pragma unroll
    for (int j = 0; j < 64; ++j) acc[j] = 0.f;
    for (int half = 0; half < 2; ++half) {
        __syncthreads();
        for (int idx = tid; idx < 64 * 128; idx += 256) {
            int k = idx & 63, j = idx >> 6;
            BsT[k][j] = WKc[j * H + half * 64 + k];
        }
        __syncthreads();
        for (int k = 0; k < 64; ++k) {
            float a = Q[i * H + half * 64 + k];
            #pragma unroll
            for (int j = 0; j < 64; ++j) acc[j] += a * BsT[k][j0 + j];
        }
    }
    for (int j = 0; j < 64; ++j) QWc[i * H + j0 + j] = acc[j];
    if (tid < 128) {
        float s = 0.f, g = 0.f;
        for (int k = 0; k < H; ++k) {
            s += Qb[k] * WKc[tid * H + k];
            g += Q[tid * H + k] * bkc[k];
        }
        qbc[tid] = s; gvec[tid] = g;
    }
    if (tid == 0) {
        float s = 0.f;
        for (int k = 0; k < H; ++k) s += Qb[k] * bkc[k];
        gsc[0] = s;
    }
}

// ---------- node GEMM: 64 rows x 128 cols per block ----------
// MODE 0: Y = X@W + B
// MODE 1: Y = relu(beta*(gelu(X)@W + B) + (1-beta)*Xold)
// MODE 2: Y += X@W + (zb[n]>0)*B       (accumulate)
template<int MODE>
__global__ __launch_bounds__(256) void node_gemm(const float* __restrict__ X,
    const float* __restrict__ W, const float* __restrict__ B, float* __restrict__ Y,
    int N, const float* __restrict__ Xold, const float* __restrict__ skipP,
    const float* __restrict__ zb)
{
    __shared__ float xs[64][132];
    int nb = blockIdx.x * 64;
    int tid = threadIdx.x;

    #pragma unroll
    for (int i = 0; i < 8; ++i) {
        int u = tid + i * 256;
        int n = u >> 5, c4 = u & 31;
        int gn = nb + n;
        float4 v = make_float4(0.f, 0.f, 0.f, 0.f);
        if (gn < N) v = *(const float4*)(X + (size_t)gn * H + c4 * 4);
        if (MODE == 1) {
            v.x = gelu_exact(v.x); v.y = gelu_exact(v.y);
            v.z = gelu_exact(v.z); v.w = gelu_exact(v.w);
        }
        xs[n][c4*4 + 0] = v.x; xs[n][c4*4 + 1] = v.y;
        xs[n][c4*4 + 2] = v.z; xs[n][c4*4 + 3] = v.w;
    }
    __syncthreads();

    int cq = tid & 15;
    int ng = tid >> 4;
    int c0 = cq * 8;
    float4 a0[4], a1[4];
    #pragma unroll
    for (int j = 0; j < 4; ++j) {
        a0[j] = make_float4(0.f,0.f,0.f,0.f);
        a1[j] = make_float4(0.f,0.f,0.f,0.f);
    }

    for (int k = 0; k < H; k += 4) {
        float xr[4][4];
        #pragma unroll
        for (int j = 0; j < 4; ++j)
            *(float4*)(&xr[j][0]) = *(const float4*)(&xs[ng*4 + j][k]);
        #pragma unroll
        for (int kk = 0; kk < 4; ++kk) {
            float4 w0 = *(const float4*)(W + (size_t)(k + kk) * H + c0);
            float4 w1 = *(const float4*)(W + (size_t)(k + kk) * H + c0 + 4);
            #pragma unroll
            for (int j = 0; j < 4; ++j) {
                float xv = xr[j][kk];
                a0[j].x += xv * w0.x; a0[j].y += xv * w0.y;
                a0[j].z += xv * w0.z; a0[j].w += xv * w0.w;
                a1[j].x += xv * w1.x; a1[j].y += xv * w1.y;
                a1[j].z += xv * w1.z; a1[j].w += xv * w1.w;
            }
        }
    }

    float4 b0 = *(const float4*)(B + c0);
    float4 b1 = *(const float4*)(B + c0 + 4);
    float beta = 0.f, omb = 0.f;
    if (MODE == 1) {
        float s = *skipP;
        beta = 1.f / (1.f + expf(-s));
        omb = 1.f - beta;
    }
    #pragma unroll
    for (int j = 0; j < 4; ++j) {
        int gn = nb + ng*4 + j;
        if (gn < N) {
            float4 r0, r1;
            r0.x = a0[j].x; r0.y = a0[j].y; r0.z = a0[j].z; r0.w = a0[j].w;
            r1.x = a1[j].x; r1.y = a1[j].y; r1.z = a1[j].z; r1.w = a1[j].w;
            if (MODE == 2) {
                float gate = (zb[gn] > 0.f) ? 1.f : 0.f;
                float4 y0 = *(const float4*)(Y + (size_t)gn * H + c0);
                float4 y1 = *(const float4*)(Y + (size_t)gn * H + c0 + 4);
                r0.x += y0.x + gate*b0.x; r0.y += y0.y + gate*b0.y;
                r0.z += y0.z + gate*b0.z; r0.w += y0.w + gate*b0.w;
                r1.x += y1.x + gate*b1.x; r1.y += y1.y + gate*b1.y;
                r1.z += y1.z + gate*b1.z; r1.w += y1.w + gate*b1.w;
            } else {
                r0.x += b0.x; r0.y += b0.y; r0.z += b0.z; r0.w += b0.w;
                r1.x += b1.x; r1.y += b1.y; r1.z += b1.z; r1.w += b1.w;
            }
            if (MODE == 1) {
                float4 o0 = *(const float4*)(Xold + (size_t)gn * H + c0);
                float4 o1 = *(const float4*)(Xold + (size_t)gn * H + c0 + 4);
                r0.x = fmaxf(beta*r0.x + omb*o0.x, 0.f);
                r0.y = fmaxf(beta*r0.y + omb*o0.y, 0.f);
                r0.z = fmaxf(beta*r0.z + omb*o0.z, 0.f);
                r0.w = fmaxf(beta*r0.w + omb*o0.w, 0.f);
                r1.x = fmaxf(beta*r1.x + omb*o1.x, 0.f);
                r1.y = fmaxf(beta*r1.y + omb*o1.y, 0.f);
                r1.z = fmaxf(beta*r1.z + omb*o1.z, 0.f);
                r1.w = fmaxf(beta*r1.w + omb*o1.w, 0.f);
            }
            *(float4*)(Y + (size_t)gn * H + c0)     = r0;
            *(float4*)(Y + (size_t)gn * H + c0 + 4) = r1;
        }
    }
}

// ---------- cvec[n] = xs[n]·gvec + gsc ----------
__global__ __launch_bounds__(256) void cvec_kernel(const float* __restrict__ X,
    const float* __restrict__ gvec, const float* __restrict__ gsc,
    float* __restrict__ cvec, int N)
{
    int t = blockIdx.x * 256 + threadIdx.x;
    int n = t >> 5, lane = t & 31;
    if (n >= N) return;
    float4 xv = *(const float4*)(X + (size_t)n * H + lane * 4);
    float4 gv = *(const float4*)(gvec + lane * 4);
    float p = xv.x*gv.x + xv.y*gv.y + xv.z*gv.z + xv.w*gv.w;
    #pragma unroll
    for (int m = 16; m >= 1; m >>= 1) p += __shfl_xor(p, m);
    if (lane == 0) cvec[n] = p + gsc[0];
}

// ---------- fused edge phase: per dst node, single pass over CSR ----------
// qtraw holds qt on entry; overwritten in place with raw = softmax-weighted sum.
__global__ __launch_bounds__(256) void gather_agg(const int* __restrict__ row_ptr,
    const int* __restrict__ col_idx, float* __restrict__ qtraw,
    const float* __restrict__ xsrc, const float* __restrict__ cvec,
    const float* __restrict__ prel, int ridx, float* __restrict__ zout, int ndt)
{
    int g = blockIdx.x * 8 + (threadIdx.x >> 5);
    int lane = threadIdx.x & 31;
    if (g >= ndt) return;
    float4 qv = *(const float4*)(qtraw + (size_t)g * H + lane * 4);
    float scale = prel[ridx] * 0.08838834764831843f;   // 1/sqrt(128)
    float cv = cvec[g];
    int beg = row_ptr[g], end = row_ptr[g + 1];
    float4 acc = make_float4(0.f, 0.f, 0.f, 0.f);
    float z = 0.f;
    for (int i = beg; i < end; ++i) {
        int s = col_idx[i];
        float4 xv = *(const float4*)(xsrc + (size_t)s * H + lane * 4);
        float p = qv.x*xv.x + qv.y*xv.y + qv.z*xv.z + qv.w*xv.w;
        #pragma unroll
        for (int m = 16; m >= 1; m >>= 1) p += __shfl_xor(p, m);
        float ev = expf((p + cv) * scale);
        z += ev;
        acc.x += ev * xv.x; acc.y += ev * xv.y;
        acc.z += ev * xv.z; acc.w += ev * xv.w;
    }
    float inv = 1.f / (z + 1e-16f);
    float4 r = make_float4(acc.x * inv, acc.y * inv, acc.z * inv, acc.w * inv);
    *(float4*)(qtraw + (size_t)g * H + lane * 4) = r;
    if (lane == 0) zout[g] = z;
}

// ---------- output head ----------
__global__ __launch_bounds__(256) void out_kernel(const float* __restrict__ X,
    const float* __restrict__ Wo, const float* __restrict__ bo,
    float* __restrict__ out, int N)
{
    int t = blockIdx.x * 256 + threadIdx.x;
    int n = t >> 5, lane = t & 31;
    if (n >= N) return;
    float4 xv = *(const float4*)(X + (size_t)n * H + lane * 4);
    float xa[4]; *(float4*)xa = xv;
    float p0 = 0.f, p1 = 0.f;
    #pragma unroll
    for (int j = 0; j < 4; ++j) {
        p0 += xa[j] * Wo[(lane*4 + j)*2 + 0];
        p1 += xa[j] * Wo[(lane*4 + j)*2 + 1];
    }
    #pragma unroll
    for (int m = 16; m >= 1; m >>= 1) { p0 += __shfl_xor(p0, m); p1 += __shfl_xor(p1, m); }
    if (lane == 0) {
        out[(size_t)n*2 + 0] = p0 + bo[0];
        out[(size_t)n*2 + 1] = p1 + bo[1];
    }
}

extern "C" void kernel_launch(void* const* d_in, const int* in_sizes, int n_in,
                              void* d_out, int out_size, void* d_ws, size_t ws_size,
                              hipStream_t stream)
{
    const float* x_tx      = (const float*)d_in[0];
    const float* x_cust    = (const float*)d_in[1];
    const int*   merch_ids = (const int*)d_in[2];
    const int*   e_ct_src  = (const int*)d_in[3];
    const int*   e_ct_dst  = (const int*)d_in[4];
    const int*   e_mt_src  = (const int*)d_in[5];
    const int*   e_mt_dst  = (const int*)d_in[6];
    const float* proj_tx_w   = (const float*)d_in[7];
    const float* proj_tx_b   = (const float*)d_in[8];
    const float* proj_cust_w = (const float*)d_in[9];
    const float* proj_cust_b = (const float*)d_in[10];
    const float* merch_emb   = (const float*)d_in[11];
    const float* kw = (const float*)d_in[12];
    const float* kb = (const float*)d_in[13];
    const float* qw = (const float*)d_in[14];
    const float* qb = (const float*)d_in[15];
    const float* vw = (const float*)d_in[16];
    const float* vb = (const float*)d_in[17];
    const float* aw = (const float*)d_in[18];
    const float* ab = (const float*)d_in[19];
    const float* skip  = (const float*)d_in[20];
    const float* a_rel = (const float*)d_in[21];
    const float* m_rel = (const float*)d_in[22];
    const float* p_rel = (const float*)d_in[23];
    const float* out_w = (const float*)d_in[24];
    const float* out_b = (const float*)d_in[25];
    (void)in_sizes; (void)n_in;

    const size_t nsz[3] = {NTX, NCU, NME};

    // workspace layout (floats, then ints) — total ~251 MB (budget measured: 256 MiB)
    float* ws = (float*)d_ws;
    size_t off = 0;
    float* xs[3];  for (int t = 0; t < 3; ++t) { xs[t] = ws + off; off += nsz[t]*H; }
    float* agg0    = ws + off; off += (size_t)NTX * H;
    float* edgebuf = ws + off; off += EDGEBUF_FLOATS;   // qt/raw (in-place); agg1,agg2 aliased in tail
    float* cvec = ws + off; off += NTX;
    float* zbuf = ws + off; off += NTX;
    float* wc   = ws + off; off += 8 * WC_STRIDE;
    float* wkc  = ws + off; off += 8 * WKC_STRIDE;
    // int area
    int* ibase = (int*)(ws + off);
    const int rp_size[4] = {NTX + 1, NTX + 1, NCU + 1, NME + 1};
    int* rowp[4]; size_t ioff = 0;
    for (int r = 0; r < 4; ++r) { rowp[r] = ibase + ioff; ioff += rp_size[r]; }
    int* colix[4];
    for (int r = 0; r < 4; ++r) { colix[r] = ibase + ioff; ioff += NEDGE; }
    int* cursor = ibase + ioff; ioff += NTX;
    int* bsum   = ibase + ioff; ioff += 256;
    size_t needed_bytes = off * sizeof(float) + ioff * sizeof(int);

    float* agg[3] = { agg0, edgebuf + AGG1_OFF, edgebuf + AGG2_OFF };

    if (ws_size < needed_bytes) {
        fill_val<<<(out_size + 255) / 256, 256, 0, stream>>>(
            (float*)d_out, out_size, (float)(ws_size >> 20));
        return;
    }

    const int src_t[4] = {1, 2, 0, 0};
    const int dst_t[4] = {0, 0, 1, 2};
    const int* esrc[4] = {e_ct_src, e_mt_src, e_ct_dst, e_mt_dst};
    const int* edst[4] = {e_ct_dst, e_mt_dst, e_ct_src, e_mt_src};

    // ---- build CSR per relation (edges constant across layers) ----
    const int egrid256 = (NEDGE + 255) / 256;
    for (int r = 0; r < 4; ++r) {
        int ndt = (int)nsz[dst_t[r]];
        int nb = (ndt + SCAN_TILE - 1) / SCAN_TILE;
        zero_int<<<(ndt + 255) / 256, 256, 0, stream>>>(cursor, ndt);   // cursor as deg
        count_deg<<<egrid256, 256, 0, stream>>>(edst[r], cursor, NEDGE);
        scan1<<<nb, 256, 0, stream>>>(cursor, rowp[r], bsum, ndt);
        scan2<<<1, 64, 0, stream>>>(bsum, nb);
        scan3<<<nb, 256, 0, stream>>>(rowp[r], bsum, ndt, NEDGE);
        copy_int<<<(ndt + 255) / 256, 256, 0, stream>>>(cursor, rowp[r], ndt);
        fill_csr<<<egrid256, 256, 0, stream>>>(esrc[r], edst[r], cursor, colix[r], NEDGE);
    }

    // precombine weights
    combine1<<<8, 256, 0, stream>>>(kw, kb, vw, vb, a_rel, m_rel, wkc, wc);
    combine2<<<8, 256, 0, stream>>>(qw, qb, wkc, wc);

    // input projections
    proj_kernel<16><<<(NTX + 1) / 2, 256, 0, stream>>>(x_tx, proj_tx_w, proj_tx_b, xs[0], NTX);
    proj_kernel<32><<<(NCU + 1) / 2, 256, 0, stream>>>(x_cust, proj_cust_w, proj_cust_b, xs[1], NCU);
    gather_rows<<<(NME * 32 + 255) / 256, 256, 0, stream>>>(merch_emb, merch_ids, xs[2], NME);

    const int agg0_4 = NTX * H / 4;

    for (int l = 0; l < NLAY; ++l) {
        fill0<<<(agg0_4 + 255) / 256, 256, 0, stream>>>((float4*)agg0, agg0_4);

        for (int r = 0; r < 4; ++r) {
            int st = src_t[r], dt = dst_t[r];
            int ndt = (int)nsz[dt];
            int combo = l * 4 + r;
            const float* QWc  = wc + (size_t)combo * WC_STRIDE;
            const float* WVc  = QWc + 16384;
            const float* qbc  = QWc + 32768;
            const float* bvc  = QWc + 32896;
            const float* gvec = QWc + 33024;
            const float* gsc  = QWc + 33152;

            // qt = xs[dt] @ QWc + qbc   (into edgebuf[0 : ndt*H])
            node_gemm<0><<<(ndt + 63) / 64, 256, 0, stream>>>(
                xs[dt], QWc, qbc, edgebuf, ndt, nullptr, nullptr, nullptr);
            cvec_kernel<<<(ndt * 32 + 255) / 256, 256, 0, stream>>>(
                xs[dt], gvec, gsc, cvec, ndt);
            // fused score+softmax+aggregate, in place over qt
            gather_agg<<<(ndt + 7) / 8, 256, 0, stream>>>(
                rowp[r], colix[r], edgebuf, xs[st], cvec, p_rel, combo, zbuf, ndt);
            // agg[dt] += raw @ WVc + (z>0)*bvc
            node_gemm<2><<<(ndt + 63) / 64, 256, 0, stream>>>(
                edgebuf, WVc, bvc, agg[dt], ndt, nullptr, nullptr, zbuf);

            // after the last full-width (tx-dst) relation has consumed edgebuf,
            // zero the aliased agg1/agg2 tail region [AGG2_OFF : EDGEBUF_FLOATS)
            if (r == 1) {
                int tail4 = (EDGEBUF_FLOATS - AGG2_OFF) / 4;
                fill0<<<(tail4 + 255) / 256, 256, 0, stream>>>(
                    (float4*)(edgebuf + AGG2_OFF), tail4);
            }
        }

        // update: xs = relu(beta*(gelu(agg)@aw + ab) + (1-beta)*xs)
        for (int t = 0; t < 3; ++t)
            node_gemm<1><<<(int)((nsz[t] + 63) / 64), 256, 0, stream>>>(
                agg[t], aw + (size_t)(l*3 + t)*H*H, ab + (size_t)(l*3 + t)*H,
                xs[t], (int)nsz[t], xs[t], skip + l*3 + t, nullptr);
    }

    out_kernel<<<(NTX * 32 + 255) / 256, 256, 0, stream>>>(xs[0], out_w, out_b, (float*)d_out, NTX);
}

// Round 5
// 1515.755 us; speedup vs baseline: 2.6625x; 1.3411x over previous
//
#include <hip/hip_runtime.h>
#include <math.h>

#define H 128
#define NTX 150000
#define NCU 40000
#define NME 10000
#define NEDGE 150000
#define NLAY 2
#define WC_STRIDE 33280     // per (l,r): QWc@0, WVc@16384, qbc@32768, bvc@32896, gvec@33024, gsc@33152
#define WKC_STRIDE 16640    // per (l,r): WKc@0, bkc@16384
#define EDGEBUF_FLOATS 19200000   // NTX*H
#define AGG2_OFF 12800000         // edgebuf offset for agg[2] (NME*H = 1.28M)
#define AGG1_OFF 14080000         // edgebuf offset for agg[1] (NCU*H = 5.12M)
#define SCAN_TILE 2048

typedef short s8v __attribute__((ext_vector_type(8)));
typedef float f32x4 __attribute__((ext_vector_type(4)));

__device__ __forceinline__ float gelu_exact(float x) {
    return 0.5f * x * (1.0f + erff(x * 0.70710678118654752f));
}
__device__ __forceinline__ unsigned short f2bf(float x) {   // RNE f32->bf16 bits
    unsigned u = __float_as_uint(x);
    return (unsigned short)((u + 0x7FFFu + ((u >> 16) & 1u)) >> 16);
}
__device__ __forceinline__ float bf2f(unsigned short b) {
    return __uint_as_float(((unsigned)b) << 16);
}

// ---------- fills ----------
__global__ __launch_bounds__(256) void fill0(float4* p, int n4) {
    int i = blockIdx.x * 256 + threadIdx.x;
    if (i < n4) p[i] = make_float4(0.f, 0.f, 0.f, 0.f);
}
__global__ __launch_bounds__(256) void fill_val(float* p, int n, float v) {
    int i = blockIdx.x * 256 + threadIdx.x;
    if (i < n) p[i] = v;
}
__global__ __launch_bounds__(256) void zero_int(int* p, int n) {
    int i = blockIdx.x * 256 + threadIdx.x;
    if (i < n) p[i] = 0;
}
__global__ __launch_bounds__(256) void copy_int(int* d, const int* s, int n) {
    int i = blockIdx.x * 256 + threadIdx.x;
    if (i < n) d[i] = s[i];
}

// ---------- CSR build ----------
__global__ __launch_bounds__(256) void count_deg(const int* __restrict__ dst,
    int* __restrict__ deg, int E)
{
    int e = blockIdx.x * 256 + threadIdx.x;
    if (e < E) atomicAdd(&deg[dst[e]], 1);
}
__global__ __launch_bounds__(256) void scan1(const int* __restrict__ deg,
    int* __restrict__ out, int* __restrict__ bsum, int n)
{
    __shared__ int ts[256];
    int tid = threadIdx.x;
    int base = blockIdx.x * SCAN_TILE + tid * 8;
    int v[8], pre[8], s = 0;
    #pragma unroll
    for (int j = 0; j < 8; ++j) {
        int idx = base + j;
        v[j] = (idx < n) ? deg[idx] : 0;
        pre[j] = s; s += v[j];
    }
    ts[tid] = s;
    __syncthreads();
    for (int off = 1; off < 256; off <<= 1) {
        int t = (tid >= off) ? ts[tid - off] : 0;
        __syncthreads();
        ts[tid] += t;
        __syncthreads();
    }
    int excl = ts[tid] - s;
    #pragma unroll
    for (int j = 0; j < 8; ++j)
        if (base + j < n) out[base + j] = excl + pre[j];
    if (tid == 255) bsum[blockIdx.x] = ts[255];
}
__global__ __launch_bounds__(64) void scan2(int* __restrict__ bsum, int nb) {
    if (threadIdx.x == 0 && blockIdx.x == 0) {
        int run = 0;
        for (int i = 0; i < nb; ++i) { int t = bsum[i]; bsum[i] = run; run += t; }
    }
}
__global__ __launch_bounds__(256) void scan3(int* __restrict__ out,
    const int* __restrict__ bsum, int n, int total)
{
    int base = blockIdx.x * SCAN_TILE;
    int add = bsum[blockIdx.x];
    for (int j = threadIdx.x; j < SCAN_TILE; j += 256) {
        int k = base + j;
        if (k < n) out[k] += add;
    }
    if (blockIdx.x == 0 && threadIdx.x == 0) out[n] = total;
}
__global__ __launch_bounds__(256) void fill_csr(const int* __restrict__ src,
    const int* __restrict__ dst, int* __restrict__ cursor, int* __restrict__ col, int E)
{
    int e = blockIdx.x * 256 + threadIdx.x;
    if (e >= E) return;
    int pos = atomicAdd(&cursor[dst[e]], 1);
    col[pos] = src[e];
}

// ---------- small projection: Y = X(NxK) @ W(KxH) + b ----------
template<int K>
__global__ __launch_bounds__(256) void proj_kernel(const float* __restrict__ X,
    const float* __restrict__ W, const float* __restrict__ B,
    float* __restrict__ Y, int N)
{
    int c = threadIdx.x & 127;
    int nl = threadIdx.x >> 7;
    int n = blockIdx.x * 2 + nl;
    if (n >= N) return;
    const float* xr = X + (size_t)n * K;
    float acc = B[c];
    #pragma unroll
    for (int k = 0; k < K; ++k) acc += xr[k] * W[k * H + c];
    Y[(size_t)n * H + c] = acc;
}

// ---------- gather rows ----------
__global__ __launch_bounds__(256) void gather_rows(const float* __restrict__ src,
    const int* __restrict__ ids, float* __restrict__ dstp, int N)
{
    int t = blockIdx.x * 256 + threadIdx.x;
    if (t >= N * 32) return;
    int n = t >> 5, c4 = t & 31;
    int sid = ids[n];
    ((float4*)dstp)[(size_t)n * 32 + c4] = ((const float4*)src)[(size_t)sid * 32 + c4];
}

// ---------- combine stage 1 ----------
__global__ __launch_bounds__(256) void combine1(const float* __restrict__ kw,
    const float* __restrict__ kb, const float* __restrict__ vw, const float* __restrict__ vb,
    const float* __restrict__ a_rel, const float* __restrict__ m_rel,
    float* __restrict__ wkc, float* __restrict__ wc)
{
    __shared__ float Bs[64][128];
    int combo = blockIdx.x;           // l*4 + r
    int l = combo >> 2, r = combo & 3;
    const int src_t[4] = {1, 2, 0, 0};
    int st = src_t[r];
    const float* Ak  = kw + (size_t)(l*3 + st) * H * H;
    const float* Akb = kb + (size_t)(l*3 + st) * H;
    const float* Av  = vw + (size_t)(l*3 + st) * H * H;
    const float* Avb = vb + (size_t)(l*3 + st) * H;
    const float* Rk = a_rel + (size_t)combo * H * H;
    const float* Rv = m_rel + (size_t)combo * H * H;
    float* WKc = wkc + (size_t)combo * WKC_STRIDE;
    float* bkc = WKc + H * H;
    float* WVc = wc + (size_t)combo * WC_STRIDE + 16384;
    float* bvc = wc + (size_t)combo * WC_STRIDE + 32896;

    int tid = threadIdx.x;
    int i = tid >> 1, j0 = (tid & 1) * 64;
    for (int pass = 0; pass < 2; ++pass) {
        const float* Ap = pass ? Av : Ak;
        const float* Rp = pass ? Rv : Rk;
        float* Out = pass ? WVc : WKc;
        float acc[64];
        #pragma unroll
        for (int j = 0; j < 64; ++j) acc[j] = 0.f;
        for (int half = 0; half < 2; ++half) {
            __syncthreads();
            for (int idx = tid; idx < 64 * 128; idx += 256)
                Bs[idx >> 7][idx & 127] = Rp[(half * 64 + (idx >> 7)) * H + (idx & 127)];
            __syncthreads();
            for (int k = 0; k < 64; ++k) {
                float a = Ap[i * H + half * 64 + k];
                #pragma unroll
                for (int j = 0; j < 64; ++j) acc[j] += a * Bs[k][j0 + j];
            }
        }
        for (int j = 0; j < 64; ++j) Out[i * H + j0 + j] = acc[j];
        __syncthreads();
    }
    if (tid < 128) {
        float s1 = 0.f, s2 = 0.f;
        for (int k = 0; k < H; ++k) {
            s1 += Akb[k] * Rk[k * H + tid];
            s2 += Avb[k] * Rv[k * H + tid];
        }
        bkc[tid] = s1; bvc[tid] = s2;
    }
}

// ---------- combine stage 2 ----------
__global__ __launch_bounds__(256) void combine2(const float* __restrict__ qw,
    const float* __restrict__ qb, const float* __restrict__ wkc, float* __restrict__ wc)
{
    __shared__ float BsT[64][128];    // BsT[k][j] = WKc[j][half*64+k]
    int combo = blockIdx.x;
    int l = combo >> 2, r = combo & 3;
    const int dst_t[4] = {0, 0, 1, 2};
    int dt = dst_t[r];
    const float* Q  = qw + (size_t)(l*3 + dt) * H * H;
    const float* Qb = qb + (size_t)(l*3 + dt) * H;
    const float* WKc = wkc + (size_t)combo * WKC_STRIDE;
    const float* bkc = WKc + H * H;
    float* QWc  = wc + (size_t)combo * WC_STRIDE;
    float* qbc  = wc + (size_t)combo * WC_STRIDE + 32768;
    float* gvec = wc + (size_t)combo * WC_STRIDE + 33024;
    float* gsc  = wc + (size_t)combo * WC_STRIDE + 33152;

    int tid = threadIdx.x;
    int i = tid >> 1, j0 = (tid & 1) * 64;
    float acc[64];
    #pragma unroll
    for (int j = 0; j < 64; ++j) acc[j] = 0.f;
    for (int half = 0; half < 2; ++half) {
        __syncthreads();
        for (int idx = tid; idx < 64 * 128; idx += 256) {
            int k = idx & 63, j = idx >> 6;
            BsT[k][j] = WKc[j * H + half * 64 + k];
        }
        __syncthreads();
        for (int k = 0; k < 64; ++k) {
            float a = Q[i * H + half * 64 + k];
            #pragma unroll
            for (int j = 0; j < 64; ++j) acc[j] += a * BsT[k][j0 + j];
        }
    }
    for (int j = 0; j < 64; ++j) QWc[i * H + j0 + j] = acc[j];
    if (tid < 128) {
        float s = 0.f, g = 0.f;
        for (int k = 0; k < H; ++k) {
            s += Qb[k] * WKc[tid * H + k];
            g += Q[tid * H + k] * bkc[k];
        }
        qbc[tid] = s; gvec[tid] = g;
    }
    if (tid == 0) {
        float s = 0.f;
        for (int k = 0; k < H; ++k) s += Qb[k] * bkc[k];
        gsc[0] = s;
    }
}

// ---------- weight prep: transpose + split f32 -> bf16 hi/lo, layout [j][k] ----------
// b = 0..15: combo = b>>1, which = b&1 (0=QWc,1=WVc); b = 16..21: aw[b-16]
__global__ __launch_bounds__(256) void wprep(const float* __restrict__ wc,
    const float* __restrict__ aw, unsigned short* __restrict__ wt)
{
    int b = blockIdx.x;
    const float* src = (b < 16)
        ? wc + (size_t)(b >> 1) * WC_STRIDE + ((b & 1) ? 16384 : 0)
        : aw + (size_t)(b - 16) * 16384;
    unsigned short* hi = wt + (size_t)b * 32768;
    unsigned short* lo = hi + 16384;
    for (int idx = threadIdx.x; idx < 16384; idx += 256) {
        int k = idx >> 7, j = idx & 127;
        float w = src[idx];
        unsigned short h = f2bf(w);
        hi[j * 128 + k] = h;
        lo[j * 128 + k] = f2bf(w - bf2f(h));
    }
}

// ---------- MFMA split-bf16 GEMM: 64 rows x 128 cols per block, K=128 ----------
// MODE 0: Y = X@W + B
// MODE 1: Y = relu(beta*(gelu(X)@W + B) + (1-beta)*Xold)
// MODE 2: Y += X@W + (zb[n]>0)*B
// Wt: [j][k] bf16 hi plane (16384) then lo plane (16384)
template<int MODE>
__global__ __launch_bounds__(256) void mfma_gemm(const float* __restrict__ X,
    const unsigned short* __restrict__ Wt, const float* __restrict__ Bias,
    float* __restrict__ Y, int N, const float* __restrict__ Xold,
    const float* __restrict__ skipP, const float* __restrict__ zb)
{
    __shared__ unsigned short lds[2][64][136];   // hi/lo planes, row stride 272 B (16-aligned)
    int tid = threadIdx.x;
    int nb = blockIdx.x * 64;

    // stage X -> bf16 hi/lo in LDS (coalesced float4 reads)
    #pragma unroll
    for (int i = 0; i < 8; ++i) {
        int u = tid + i * 256;
        int n = u >> 5, c4 = u & 31;
        int gn = nb + n;
        float4 v = make_float4(0.f, 0.f, 0.f, 0.f);
        if (gn < N) v = *(const float4*)(X + (size_t)gn * H + c4 * 4);
        if (MODE == 1) {
            v.x = gelu_exact(v.x); v.y = gelu_exact(v.y);
            v.z = gelu_exact(v.z); v.w = gelu_exact(v.w);
        }
        ushort4 h, lo;
        h.x = f2bf(v.x); lo.x = f2bf(v.x - bf2f(h.x));
        h.y = f2bf(v.y); lo.y = f2bf(v.y - bf2f(h.y));
        h.z = f2bf(v.z); lo.z = f2bf(v.z - bf2f(h.z));
        h.w = f2bf(v.w); lo.w = f2bf(v.w - bf2f(h.w));
        *(ushort4*)&lds[0][n][c4 * 4] = h;
        *(ushort4*)&lds[1][n][c4 * 4] = lo;
    }
    __syncthreads();

    int wid = tid >> 6, lane = tid & 63;
    int l15 = lane & 15, kg = lane >> 4;
    int col0 = wid * 32;

    // B (weight) fragments in registers: [n][kb], hi+lo
    s8v bhi[2][4], blo[2][4];
    #pragma unroll
    for (int n = 0; n < 2; ++n) {
        int j = col0 + n * 16 + l15;
        #pragma unroll
        for (int kb = 0; kb < 4; ++kb) {
            bhi[n][kb] = *(const s8v*)(Wt + (size_t)j * 128 + kb * 32 + kg * 8);
            blo[n][kb] = *(const s8v*)(Wt + 16384 + (size_t)j * 128 + kb * 32 + kg * 8);
        }
    }

    f32x4 acc[4][2];
    #pragma unroll
    for (int m = 0; m < 4; ++m)
        #pragma unroll
        for (int n = 0; n < 2; ++n)
            acc[m][n] = (f32x4){0.f, 0.f, 0.f, 0.f};

    #pragma unroll
    for (int m = 0; m < 4; ++m) {
        int row = m * 16 + l15;
        #pragma unroll
        for (int kb = 0; kb < 4; ++kb) {
            s8v ah = *(const s8v*)&lds[0][row][kb * 32 + kg * 8];
            s8v al = *(const s8v*)&lds[1][row][kb * 32 + kg * 8];
            #pragma unroll
            for (int n = 0; n < 2; ++n) {
                acc[m][n] = __builtin_amdgcn_mfma_f32_16x16x32_bf16(ah, bhi[n][kb], acc[m][n], 0, 0, 0);
                acc[m][n] = __builtin_amdgcn_mfma_f32_16x16x32_bf16(al, bhi[n][kb], acc[m][n], 0, 0, 0);
                acc[m][n] = __builtin_amdgcn_mfma_f32_16x16x32_bf16(ah, blo[n][kb], acc[m][n], 0, 0, 0);
            }
        }
    }

    float beta = 0.f, omb = 0.f;
    if (MODE == 1) {
        float s = *skipP;
        beta = 1.f / (1.f + expf(-s));
        omb = 1.f - beta;
    }
    float bias0 = Bias[col0 + l15];
    float bias1 = Bias[col0 + 16 + l15];

    #pragma unroll
    for (int m = 0; m < 4; ++m) {
        #pragma unroll
        for (int r = 0; r < 4; ++r) {
            int grow = nb + m * 16 + kg * 4 + r;
            if (grow < N) {
                float gate = 1.f;
                if (MODE == 2) gate = (zb[grow] > 0.f) ? 1.f : 0.f;
                #pragma unroll
                for (int n = 0; n < 2; ++n) {
                    int col = col0 + n * 16 + l15;
                    float val = acc[m][n][r];
                    float bs = n ? bias1 : bias0;
                    size_t yi = (size_t)grow * H + col;
                    if (MODE == 0) {
                        Y[yi] = val + bs;
                    } else if (MODE == 2) {
                        Y[yi] += val + gate * bs;
                    } else {
                        float o = val + bs;
                        float xo = Xold[yi];
                        Y[yi] = fmaxf(beta * o + omb * xo, 0.f);
                    }
                }
            }
        }
    }
}

// ---------- cvec[n] = xs[n]·gvec + gsc ----------
__global__ __launch_bounds__(256) void cvec_kernel(const float* __restrict__ X,
    const float* __restrict__ gvec, const float* __restrict__ gsc,
    float* __restrict__ cvec, int N)
{
    int t = blockIdx.x * 256 + threadIdx.x;
    int n = t >> 5, lane = t & 31;
    if (n >= N) return;
    float4 xv = *(const float4*)(X + (size_t)n * H + lane * 4);
    float4 gv = *(const float4*)(gvec + lane * 4);
    float p = xv.x*gv.x + xv.y*gv.y + xv.z*gv.z + xv.w*gv.w;
    #pragma unroll
    for (int m = 16; m >= 1; m >>= 1) p += __shfl_xor(p, m);
    if (lane == 0) cvec[n] = p + gsc[0];
}

// ---------- fused edge phase: per dst node, single pass over CSR ----------
__global__ __launch_bounds__(256) void gather_agg(const int* __restrict__ row_ptr,
    const int* __restrict__ col_idx, float* __restrict__ qtraw,
    const float* __restrict__ xsrc, const float* __restrict__ cvec,
    const float* __restrict__ prel, int ridx, float* __restrict__ zout, int ndt)
{
    int g = blockIdx.x * 8 + (threadIdx.x >> 5);
    int lane = threadIdx.x & 31;
    if (g >= ndt) return;
    float4 qv = *(const float4*)(qtraw + (size_t)g * H + lane * 4);
    float scale = prel[ridx] * 0.08838834764831843f;   // 1/sqrt(128)
    float cv = cvec[g];
    int beg = row_ptr[g], end = row_ptr[g + 1];
    float4 acc = make_float4(0.f, 0.f, 0.f, 0.f);
    float z = 0.f;
    for (int i = beg; i < end; ++i) {
        int s = col_idx[i];
        float4 xv = *(const float4*)(xsrc + (size_t)s * H + lane * 4);
        float p = qv.x*xv.x + qv.y*xv.y + qv.z*xv.z + qv.w*xv.w;
        #pragma unroll
        for (int m = 16; m >= 1; m >>= 1) p += __shfl_xor(p, m);
        float ev = expf((p + cv) * scale);
        z += ev;
        acc.x += ev * xv.x; acc.y += ev * xv.y;
        acc.z += ev * xv.z; acc.w += ev * xv.w;
    }
    float inv = 1.f / (z + 1e-16f);
    float4 r = make_float4(acc.x * inv, acc.y * inv, acc.z * inv, acc.w * inv);
    *(float4*)(qtraw + (size_t)g * H + lane * 4) = r;
    if (lane == 0) zout[g] = z;
}

// ---------- output head ----------
__global__ __launch_bounds__(256) void out_kernel(const float* __restrict__ X,
    const float* __restrict__ Wo, const float* __restrict__ bo,
    float* __restrict__ out, int N)
{
    int t = blockIdx.x * 256 + threadIdx.x;
    int n = t >> 5, lane = t & 31;
    if (n >= N) return;
    float4 xv = *(const float4*)(X + (size_t)n * H + lane * 4);
    float xa[4]; *(float4*)xa = xv;
    float p0 = 0.f, p1 = 0.f;
    #pragma unroll
    for (int j = 0; j < 4; ++j) {
        p0 += xa[j] * Wo[(lane*4 + j)*2 + 0];
        p1 += xa[j] * Wo[(lane*4 + j)*2 + 1];
    }
    #pragma unroll
    for (int m = 16; m >= 1; m >>= 1) { p0 += __shfl_xor(p0, m); p1 += __shfl_xor(p1, m); }
    if (lane == 0) {
        out[(size_t)n*2 + 0] = p0 + bo[0];
        out[(size_t)n*2 + 1] = p1 + bo[1];
    }
}

extern "C" void kernel_launch(void* const* d_in, const int* in_sizes, int n_in,
                              void* d_out, int out_size, void* d_ws, size_t ws_size,
                              hipStream_t stream)
{
    const float* x_tx      = (const float*)d_in[0];
    const float* x_cust    = (const float*)d_in[1];
    const int*   merch_ids = (const int*)d_in[2];
    const int*   e_ct_src  = (const int*)d_in[3];
    const int*   e_ct_dst  = (const int*)d_in[4];
    const int*   e_mt_src  = (const int*)d_in[5];
    const int*   e_mt_dst  = (const int*)d_in[6];
    const float* proj_tx_w   = (const float*)d_in[7];
    const float* proj_tx_b   = (const float*)d_in[8];
    const float* proj_cust_w = (const float*)d_in[9];
    const float* proj_cust_b = (const float*)d_in[10];
    const float* merch_emb   = (const float*)d_in[11];
    const float* kw = (const float*)d_in[12];
    const float* kb = (const float*)d_in[13];
    const float* qw = (const float*)d_in[14];
    const float* qb = (const float*)d_in[15];
    const float* vw = (const float*)d_in[16];
    const float* vb = (const float*)d_in[17];
    const float* aw = (const float*)d_in[18];
    const float* ab = (const float*)d_in[19];
    const float* skip  = (const float*)d_in[20];
    const float* a_rel = (const float*)d_in[21];
    const float* m_rel = (const float*)d_in[22];
    const float* p_rel = (const float*)d_in[23];
    const float* out_w = (const float*)d_in[24];
    const float* out_b = (const float*)d_in[25];
    (void)in_sizes; (void)n_in;

    const size_t nsz[3] = {NTX, NCU, NME};

    // workspace layout (floats, then ints, then bf16 weight planes) — ~264.7 MB of 256 MiB
    float* ws = (float*)d_ws;
    size_t off = 0;
    float* xs[3];  for (int t = 0; t < 3; ++t) { xs[t] = ws + off; off += nsz[t]*H; }
    float* agg0    = ws + off; off += (size_t)NTX * H;
    float* edgebuf = ws + off; off += EDGEBUF_FLOATS;   // qt/raw (in-place); agg1,agg2 aliased in tail
    float* cvec = ws + off; off += NTX;
    float* zbuf = ws + off; off += NTX;
    float* wc   = ws + off; off += 8 * WC_STRIDE;
    float* wkc  = ws + off; off += 8 * WKC_STRIDE;
    // int area
    int* ibase = (int*)(ws + off);
    const int rp_size[4] = {NTX + 1, NTX + 1, NCU + 1, NME + 1};
    int* rowp[4]; size_t ioff = 0;
    for (int r = 0; r < 4; ++r) { rowp[r] = ibase + ioff; ioff += rp_size[r]; }
    int* colix[4];
    for (int r = 0; r < 4; ++r) { colix[r] = ibase + ioff; ioff += NEDGE; }
    int* cursor = ibase + ioff; ioff += NTX;
    int* bsum   = ibase + ioff; ioff += 256;
    // bf16 weight planes: 22 matrices x (hi 16384 + lo 16384) ushorts
    unsigned short* wt = (unsigned short*)(ibase + ioff);
    size_t needed_bytes = off * sizeof(float) + ioff * sizeof(int)
                        + (size_t)22 * 32768 * sizeof(unsigned short);

    float* agg[3] = { agg0, edgebuf + AGG1_OFF, edgebuf + AGG2_OFF };

    if (ws_size < needed_bytes) {
        fill_val<<<(out_size + 255) / 256, 256, 0, stream>>>(
            (float*)d_out, out_size, (float)(ws_size >> 20));
        return;
    }

    const int src_t[4] = {1, 2, 0, 0};
    const int dst_t[4] = {0, 0, 1, 2};
    const int* esrc[4] = {e_ct_src, e_mt_src, e_ct_dst, e_mt_dst};
    const int* edst[4] = {e_ct_dst, e_mt_dst, e_ct_src, e_mt_src};

    // ---- build CSR per relation (edges constant across layers) ----
    const int egrid256 = (NEDGE + 255) / 256;
    for (int r = 0; r < 4; ++r) {
        int ndt = (int)nsz[dst_t[r]];
        int nb = (ndt + SCAN_TILE - 1) / SCAN_TILE;
        zero_int<<<(ndt + 255) / 256, 256, 0, stream>>>(cursor, ndt);   // cursor as deg
        count_deg<<<egrid256, 256, 0, stream>>>(edst[r], cursor, NEDGE);
        scan1<<<nb, 256, 0, stream>>>(cursor, rowp[r], bsum, ndt);
        scan2<<<1, 64, 0, stream>>>(bsum, nb);
        scan3<<<nb, 256, 0, stream>>>(rowp[r], bsum, ndt, NEDGE);
        copy_int<<<(ndt + 255) / 256, 256, 0, stream>>>(cursor, rowp[r], ndt);
        fill_csr<<<egrid256, 256, 0, stream>>>(esrc[r], edst[r], cursor, colix[r], NEDGE);
    }

    // precombine weights, then bf16 hi/lo transposed planes
    combine1<<<8, 256, 0, stream>>>(kw, kb, vw, vb, a_rel, m_rel, wkc, wc);
    combine2<<<8, 256, 0, stream>>>(qw, qb, wkc, wc);
    wprep<<<22, 256, 0, stream>>>(wc, aw, wt);

    // input projections
    proj_kernel<16><<<(NTX + 1) / 2, 256, 0, stream>>>(x_tx, proj_tx_w, proj_tx_b, xs[0], NTX);
    proj_kernel<32><<<(NCU + 1) / 2, 256, 0, stream>>>(x_cust, proj_cust_w, proj_cust_b, xs[1], NCU);
    gather_rows<<<(NME * 32 + 255) / 256, 256, 0, stream>>>(merch_emb, merch_ids, xs[2], NME);

    const int agg0_4 = NTX * H / 4;

    for (int l = 0; l < NLAY; ++l) {
        fill0<<<(agg0_4 + 255) / 256, 256, 0, stream>>>((float4*)agg0, agg0_4);

        for (int r = 0; r < 4; ++r) {
            int st = src_t[r], dt = dst_t[r];
            int ndt = (int)nsz[dt];
            int combo = l * 4 + r;
            const float* QWc  = wc + (size_t)combo * WC_STRIDE;
            const float* qbc  = QWc + 32768;
            const float* bvc  = QWc + 32896;
            const float* gvec = QWc + 33024;
            const float* gsc  = QWc + 33152;
            const unsigned short* wtQ = wt + (size_t)(combo * 2 + 0) * 32768;
            const unsigned short* wtV = wt + (size_t)(combo * 2 + 1) * 32768;

            // qt = xs[dt] @ QWc + qbc   (into edgebuf[0 : ndt*H])
            mfma_gemm<0><<<(ndt + 63) / 64, 256, 0, stream>>>(
                xs[dt], wtQ, qbc, edgebuf, ndt, nullptr, nullptr, nullptr);
            cvec_kernel<<<(ndt * 32 + 255) / 256, 256, 0, stream>>>(
                xs[dt], gvec, gsc, cvec, ndt);
            // fused score+softmax+aggregate, in place over qt
            gather_agg<<<(ndt + 7) / 8, 256, 0, stream>>>(
                rowp[r], colix[r], edgebuf, xs[st], cvec, p_rel, combo, zbuf, ndt);
            // agg[dt] += raw @ WVc + (z>0)*bvc
            mfma_gemm<2><<<(ndt + 63) / 64, 256, 0, stream>>>(
                edgebuf, wtV, bvc, agg[dt], ndt, nullptr, nullptr, zbuf);

            // after the last full-width (tx-dst) relation has consumed edgebuf,
            // zero the aliased agg1/agg2 tail region [AGG2_OFF : EDGEBUF_FLOATS)
            if (r == 1) {
                int tail4 = (EDGEBUF_FLOATS - AGG2_OFF) / 4;
                fill0<<<(tail4 + 255) / 256, 256, 0, stream>>>(
                    (float4*)(edgebuf + AGG2_OFF), tail4);
            }
        }

        // update: xs = relu(beta*(gelu(agg)@aw + ab) + (1-beta)*xs)
        for (int t = 0; t < 3; ++t)
            mfma_gemm<1><<<(int)((nsz[t] + 63) / 64), 256, 0, stream>>>(
                agg[t], wt + (size_t)(16 + l*3 + t) * 32768,
                ab + (size_t)(l*3 + t)*H, xs[t], (int)nsz[t],
                xs[t], skip + l*3 + t, nullptr);
    }

    out_kernel<<<(NTX * 32 + 255) / 256, 256, 0, stream>>>(xs[0], out_w, out_b, (float*)d_out, NTX);
}

// Round 6
// 1333.586 us; speedup vs baseline: 3.0262x; 1.1366x over previous
//
#include <hip/hip_runtime.h>
#include <math.h>

#define H 128
#define NTX 150000
#define NCU 40000
#define NME 10000
#define NEDGE 150000
#define NLAY 2
#define WC_STRIDE 33280     // per (l,r): QWc@0, WVc@16384, qbc@32768, bvc@32896, gvec@33024, gsc@33152
#define WKC_STRIDE 16640    // per (l,r): WKc@0, bkc@16384
#define EDGEBUF_FLOATS 19200000   // NTX*H
#define AGG2_OFF 12800000         // edgebuf offset for agg[2] (NME*H = 1.28M)
#define AGG1_OFF 14080000         // edgebuf offset for agg[1] (NCU*H = 5.12M)
#define SCAN_TILE 2048

typedef short s8v __attribute__((ext_vector_type(8)));
typedef float f32x4 __attribute__((ext_vector_type(4)));

__device__ __forceinline__ float gelu_exact(float x) {
    return 0.5f * x * (1.0f + erff(x * 0.70710678118654752f));
}
__device__ __forceinline__ unsigned short f2bf(float x) {   // RNE f32->bf16 bits
    unsigned u = __float_as_uint(x);
    return (unsigned short)((u + 0x7FFFu + ((u >> 16) & 1u)) >> 16);
}
__device__ __forceinline__ float bf2f(unsigned short b) {
    return __uint_as_float(((unsigned)b) << 16);
}

// ---------- fills ----------
__global__ __launch_bounds__(256) void fill_val(float* p, int n, float v) {
    int i = blockIdx.x * 256 + threadIdx.x;
    if (i < n) p[i] = v;
}
__global__ __launch_bounds__(256) void zero_int(int* p, int n) {
    int i = blockIdx.x * 256 + threadIdx.x;
    if (i < n) p[i] = 0;
}
__global__ __launch_bounds__(256) void copy_int(int* d, const int* s, int n) {
    int i = blockIdx.x * 256 + threadIdx.x;
    if (i < n) d[i] = s[i];
}

// ---------- CSR build ----------
__global__ __launch_bounds__(256) void count_deg(const int* __restrict__ dst,
    int* __restrict__ deg, int E)
{
    int e = blockIdx.x * 256 + threadIdx.x;
    if (e < E) atomicAdd(&deg[dst[e]], 1);
}
__global__ __launch_bounds__(256) void scan1(const int* __restrict__ deg,
    int* __restrict__ out, int* __restrict__ bsum, int n)
{
    __shared__ int ts[256];
    int tid = threadIdx.x;
    int base = blockIdx.x * SCAN_TILE + tid * 8;
    int v[8], pre[8], s = 0;
    #pragma unroll
    for (int j = 0; j < 8; ++j) {
        int idx = base + j;
        v[j] = (idx < n) ? deg[idx] : 0;
        pre[j] = s; s += v[j];
    }
    ts[tid] = s;
    __syncthreads();
    for (int off = 1; off < 256; off <<= 1) {
        int t = (tid >= off) ? ts[tid - off] : 0;
        __syncthreads();
        ts[tid] += t;
        __syncthreads();
    }
    int excl = ts[tid] - s;
    #pragma unroll
    for (int j = 0; j < 8; ++j)
        if (base + j < n) out[base + j] = excl + pre[j];
    if (tid == 255) bsum[blockIdx.x] = ts[255];
}
__global__ __launch_bounds__(64) void scan2(int* __restrict__ bsum, int nb) {
    if (threadIdx.x == 0 && blockIdx.x == 0) {
        int run = 0;
        for (int i = 0; i < nb; ++i) { int t = bsum[i]; bsum[i] = run; run += t; }
    }
}
__global__ __launch_bounds__(256) void scan3(int* __restrict__ out,
    const int* __restrict__ bsum, int n, int total)
{
    int base = blockIdx.x * SCAN_TILE;
    int add = bsum[blockIdx.x];
    for (int j = threadIdx.x; j < SCAN_TILE; j += 256) {
        int k = base + j;
        if (k < n) out[k] += add;
    }
    if (blockIdx.x == 0 && threadIdx.x == 0) out[n] = total;
}
__global__ __launch_bounds__(256) void fill_csr(const int* __restrict__ src,
    const int* __restrict__ dst, int* __restrict__ cursor, int* __restrict__ col, int E)
{
    int e = blockIdx.x * 256 + threadIdx.x;
    if (e >= E) return;
    int pos = atomicAdd(&cursor[dst[e]], 1);
    col[pos] = src[e];
}

// ---------- small projection: Y = X(NxK) @ W(KxH) + b ----------
template<int K>
__global__ __launch_bounds__(256) void proj_kernel(const float* __restrict__ X,
    const float* __restrict__ W, const float* __restrict__ B,
    float* __restrict__ Y, int N)
{
    int c = threadIdx.x & 127;
    int nl = threadIdx.x >> 7;
    int n = blockIdx.x * 2 + nl;
    if (n >= N) return;
    const float* xr = X + (size_t)n * K;
    float acc = B[c];
    #pragma unroll
    for (int k = 0; k < K; ++k) acc += xr[k] * W[k * H + c];
    Y[(size_t)n * H + c] = acc;
}

// ---------- gather rows ----------
__global__ __launch_bounds__(256) void gather_rows(const float* __restrict__ src,
    const int* __restrict__ ids, float* __restrict__ dstp, int N)
{
    int t = blockIdx.x * 256 + threadIdx.x;
    if (t >= N * 32) return;
    int n = t >> 5, c4 = t & 31;
    int sid = ids[n];
    ((float4*)dstp)[(size_t)n * 32 + c4] = ((const float4*)src)[(size_t)sid * 32 + c4];
}

// ---------- combine stage 1 (parallel, 64 blocks) ----------
// b: combo = b>>3 (8), pass = (b>>2)&1 (0=K,1=V), slice = b&3 (32 rows each)
__global__ __launch_bounds__(256) void combine1_par(const float* __restrict__ kw,
    const float* __restrict__ kb, const float* __restrict__ vw, const float* __restrict__ vb,
    const float* __restrict__ a_rel, const float* __restrict__ m_rel,
    float* __restrict__ wkc, float* __restrict__ wc)
{
    __shared__ float Rs[64][132];
    int b = blockIdx.x;
    int combo = b >> 3;
    int pass  = (b >> 2) & 1;
    int slice = b & 3;
    int l = combo >> 2, r = combo & 3;
    const int src_t[4] = {1, 2, 0, 0};
    int st = src_t[r];
    const float* Ap = (pass ? vw : kw) + (size_t)(l*3 + st) * H * H;
    const float* Rp = (pass ? m_rel : a_rel) + (size_t)combo * H * H;
    float* Out = pass ? (wc + (size_t)combo * WC_STRIDE + 16384)
                      : (wkc + (size_t)combo * WKC_STRIDE);

    int tid = threadIdx.x;
    int i = slice * 32 + (tid >> 3);
    int jb = tid & 7;
    float acc[16];
    #pragma unroll
    for (int j = 0; j < 16; ++j) acc[j] = 0.f;

    for (int half = 0; half < 2; ++half) {
        __syncthreads();
        for (int idx = tid; idx < 64 * 128; idx += 256)
            Rs[idx >> 7][idx & 127] = Rp[(half * 64 + (idx >> 7)) * H + (idx & 127)];
        __syncthreads();
        for (int k = 0; k < 64; ++k) {
            float a = Ap[i * H + half * 64 + k];
            #pragma unroll
            for (int j = 0; j < 16; ++j) acc[j] += a * Rs[k][jb + j * 8];
        }
    }
    #pragma unroll
    for (int j = 0; j < 16; ++j) Out[i * H + jb + j * 8] = acc[j];

    if (pass == 0 && slice == 0) {
        const float* Akb = kb + (size_t)(l*3 + st) * H;
        const float* Avb = vb + (size_t)(l*3 + st) * H;
        const float* Rk = a_rel + (size_t)combo * H * H;
        const float* Rv = m_rel + (size_t)combo * H * H;
        float* bkc = wkc + (size_t)combo * WKC_STRIDE + H * H;
        float* bvc = wc + (size_t)combo * WC_STRIDE + 32896;
        if (tid < 128) {
            float s = 0.f;
            for (int k = 0; k < H; ++k) s += Akb[k] * Rk[k * H + tid];
            bkc[tid] = s;
        } else {
            int c = tid - 128;
            float s = 0.f;
            for (int k = 0; k < H; ++k) s += Avb[k] * Rv[k * H + c];
            bvc[c] = s;
        }
    }
}

// ---------- combine stage 2 (parallel, 32 blocks): QWc = qw[dt] @ WKc^T ----------
__global__ __launch_bounds__(256) void combine2_par(const float* __restrict__ qw,
    const float* __restrict__ qb, const float* __restrict__ wkc, float* __restrict__ wc)
{
    __shared__ float BsT[64][133];    // BsT[k][j] = WKc[j][half*64+k]
    int b = blockIdx.x;
    int combo = b >> 2;
    int slice = b & 3;
    int l = combo >> 2, r = combo & 3;
    const int dst_t[4] = {0, 0, 1, 2};
    int dt = dst_t[r];
    const float* Q  = qw + (size_t)(l*3 + dt) * H * H;
    const float* Qb = qb + (size_t)(l*3 + dt) * H;
    const float* WKc = wkc + (size_t)combo * WKC_STRIDE;
    const float* bkc = WKc + H * H;
    float* QWc = wc + (size_t)combo * WC_STRIDE;

    int tid = threadIdx.x;
    int i = slice * 32 + (tid >> 3);
    int jb = tid & 7;
    float acc[16];
    #pragma unroll
    for (int j = 0; j < 16; ++j) acc[j] = 0.f;

    for (int half = 0; half < 2; ++half) {
        __syncthreads();
        for (int idx = tid; idx < 64 * 128; idx += 256) {
            int j = idx >> 6, k = idx & 63;
            BsT[k][j] = WKc[j * H + half * 64 + k];
        }
        __syncthreads();
        for (int k = 0; k < 64; ++k) {
            float a = Q[i * H + half * 64 + k];
            #pragma unroll
            for (int j = 0; j < 16; ++j) acc[j] += a * BsT[k][jb + j * 8];
        }
    }
    #pragma unroll
    for (int j = 0; j < 16; ++j) QWc[i * H + jb + j * 8] = acc[j];

    if (slice == 0) {
        float* qbc  = wc + (size_t)combo * WC_STRIDE + 32768;
        float* gvec = wc + (size_t)combo * WC_STRIDE + 33024;
        float* gsc  = wc + (size_t)combo * WC_STRIDE + 33152;
        if (tid < 128) {
            float s = 0.f;
            for (int k = 0; k < H; ++k) s += Qb[k] * WKc[tid * H + k];
            qbc[tid] = s;
            if (tid == 0) {
                float g = 0.f;
                for (int k = 0; k < H; ++k) g += Qb[k] * bkc[k];
                gsc[0] = g;
            }
        } else {
            int c = tid - 128;
            float s = 0.f;
            for (int k = 0; k < H; ++k) s += Q[c * H + k] * bkc[k];
            gvec[c] = s;
        }
    }
}

// ---------- weight prep: transpose + split f32 -> bf16 hi/lo, layout [j][k] ----------
__global__ __launch_bounds__(256) void wprep(const float* __restrict__ wc,
    const float* __restrict__ aw, unsigned short* __restrict__ wt)
{
    int b = blockIdx.x;
    const float* src = (b < 16)
        ? wc + (size_t)(b >> 1) * WC_STRIDE + ((b & 1) ? 16384 : 0)
        : aw + (size_t)(b - 16) * 16384;
    unsigned short* hi = wt + (size_t)b * 32768;
    unsigned short* lo = hi + 16384;
    for (int idx = threadIdx.x; idx < 16384; idx += 256) {
        int k = idx >> 7, j = idx & 127;
        float w = src[idx];
        unsigned short h = f2bf(w);
        hi[j * 128 + k] = h;
        lo[j * 128 + k] = f2bf(w - bf2f(h));
    }
}

// ---------- MFMA split-bf16 GEMM: 64 rows x 128 cols per block, K=128 ----------
// MODE 0: Y = X@W + B                          (+ optional fused cvec via HASCV)
// MODE 1: Y = relu(beta*(gelu(X)@W + B) + (1-beta)*Xold)
// MODE 2: Y += X@W + gate*B        (accumulate; gate = zb[n]>0)
// MODE 3: Y  = X@W + gate*B        (first-relation overwrite; gate = zb[n]>0)
template<int MODE, int HASCV>
__global__ __launch_bounds__(256) void mfma_gemm(const float* __restrict__ X,
    const unsigned short* __restrict__ Wt, const float* __restrict__ Bias,
    float* __restrict__ Y, int N, const float* __restrict__ Xold,
    const float* __restrict__ skipP, const float* __restrict__ zb,
    const float* __restrict__ gvecp, const float* __restrict__ gscp,
    float* __restrict__ cvecout)
{
    __shared__ unsigned short lds[2][64][136];   // hi/lo planes, row stride 272 B
    __shared__ float cacc[64];
    int tid = threadIdx.x;
    int nb = blockIdx.x * 64;

    if (HASCV) {
        if (tid < 64) cacc[tid] = 0.f;
        __syncthreads();
    }

    // stage X -> bf16 hi/lo in LDS (coalesced float4 reads); fuse cvec partial dots
    #pragma unroll
    for (int i = 0; i < 8; ++i) {
        int u = tid + i * 256;
        int n = u >> 5, c4 = u & 31;
        int gn = nb + n;
        float4 v = make_float4(0.f, 0.f, 0.f, 0.f);
        if (gn < N) v = *(const float4*)(X + (size_t)gn * H + c4 * 4);
        if (HASCV) {
            float4 gv = *(const float4*)(gvecp + c4 * 4);
            float part = v.x*gv.x + v.y*gv.y + v.z*gv.z + v.w*gv.w;
            atomicAdd(&cacc[n], part);
        }
        if (MODE == 1) {
            v.x = gelu_exact(v.x); v.y = gelu_exact(v.y);
            v.z = gelu_exact(v.z); v.w = gelu_exact(v.w);
        }
        ushort4 h, lo;
        h.x = f2bf(v.x); lo.x = f2bf(v.x - bf2f(h.x));
        h.y = f2bf(v.y); lo.y = f2bf(v.y - bf2f(h.y));
        h.z = f2bf(v.z); lo.z = f2bf(v.z - bf2f(h.z));
        h.w = f2bf(v.w); lo.w = f2bf(v.w - bf2f(h.w));
        *(ushort4*)&lds[0][n][c4 * 4] = h;
        *(ushort4*)&lds[1][n][c4 * 4] = lo;
    }
    __syncthreads();

    if (HASCV) {
        if (tid < 64 && nb + tid < N) cvecout[nb + tid] = cacc[tid] + gscp[0];
    }

    int wid = tid >> 6, lane = tid & 63;
    int l15 = lane & 15, kg = lane >> 4;
    int col0 = wid * 32;

    // B (weight) fragments in registers: [n][kb], hi+lo
    s8v bhi[2][4], blo[2][4];
    #pragma unroll
    for (int n = 0; n < 2; ++n) {
        int j = col0 + n * 16 + l15;
        #pragma unroll
        for (int kb = 0; kb < 4; ++kb) {
            bhi[n][kb] = *(const s8v*)(Wt + (size_t)j * 128 + kb * 32 + kg * 8);
            blo[n][kb] = *(const s8v*)(Wt + 16384 + (size_t)j * 128 + kb * 32 + kg * 8);
        }
    }

    f32x4 acc[4][2];
    #pragma unroll
    for (int m = 0; m < 4; ++m)
        #pragma unroll
        for (int n = 0; n < 2; ++n)
            acc[m][n] = (f32x4){0.f, 0.f, 0.f, 0.f};

    #pragma unroll
    for (int m = 0; m < 4; ++m) {
        int row = m * 16 + l15;
        #pragma unroll
        for (int kb = 0; kb < 4; ++kb) {
            s8v ah = *(const s8v*)&lds[0][row][kb * 32 + kg * 8];
            s8v al = *(const s8v*)&lds[1][row][kb * 32 + kg * 8];
            #pragma unroll
            for (int n = 0; n < 2; ++n) {
                acc[m][n] = __builtin_amdgcn_mfma_f32_16x16x32_bf16(ah, bhi[n][kb], acc[m][n], 0, 0, 0);
                acc[m][n] = __builtin_amdgcn_mfma_f32_16x16x32_bf16(al, bhi[n][kb], acc[m][n], 0, 0, 0);
                acc[m][n] = __builtin_amdgcn_mfma_f32_16x16x32_bf16(ah, blo[n][kb], acc[m][n], 0, 0, 0);
            }
        }
    }

    float beta = 0.f, omb = 0.f;
    if (MODE == 1) {
        float s = *skipP;
        beta = 1.f / (1.f + expf(-s));
        omb = 1.f - beta;
    }
    float bias0 = Bias[col0 + l15];
    float bias1 = Bias[col0 + 16 + l15];

    #pragma unroll
    for (int m = 0; m < 4; ++m) {
        #pragma unroll
        for (int r = 0; r < 4; ++r) {
            int grow = nb + m * 16 + kg * 4 + r;
            if (grow < N) {
                float gate = 1.f;
                if (MODE == 2 || MODE == 3) gate = (zb[grow] > 0.f) ? 1.f : 0.f;
                #pragma unroll
                for (int n = 0; n < 2; ++n) {
                    int col = col0 + n * 16 + l15;
                    float val = acc[m][n][r];
                    float bs = n ? bias1 : bias0;
                    size_t yi = (size_t)grow * H + col;
                    if (MODE == 0) {
                        Y[yi] = val + bs;
                    } else if (MODE == 3) {
                        Y[yi] = val + gate * bs;
                    } else if (MODE == 2) {
                        Y[yi] += val + gate * bs;
                    } else {
                        float o = val + bs;
                        float xo = Xold[yi];
                        Y[yi] = fmaxf(beta * o + omb * xo, 0.f);
                    }
                }
            }
        }
    }
}

// ---------- fused edge phase: per dst node, single pass over CSR ----------
__global__ __launch_bounds__(256) void gather_agg(const int* __restrict__ row_ptr,
    const int* __restrict__ col_idx, float* __restrict__ qtraw,
    const float* __restrict__ xsrc, const float* __restrict__ cvec,
    const float* __restrict__ prel, int ridx, float* __restrict__ zout, int ndt)
{
    int g = blockIdx.x * 8 + (threadIdx.x >> 5);
    int lane = threadIdx.x & 31;
    if (g >= ndt) return;
    float4 qv = *(const float4*)(qtraw + (size_t)g * H + lane * 4);
    float scale = prel[ridx] * 0.08838834764831843f;   // 1/sqrt(128)
    float cv = cvec[g];
    int beg = row_ptr[g], end = row_ptr[g + 1];
    float4 acc = make_float4(0.f, 0.f, 0.f, 0.f);
    float z = 0.f;
    for (int i = beg; i < end; ++i) {
        int s = col_idx[i];
        float4 xv = *(const float4*)(xsrc + (size_t)s * H + lane * 4);
        float p = qv.x*xv.x + qv.y*xv.y + qv.z*xv.z + qv.w*xv.w;
        #pragma unroll
        for (int m = 16; m >= 1; m >>= 1) p += __shfl_xor(p, m);
        float ev = expf((p + cv) * scale);
        z += ev;
        acc.x += ev * xv.x; acc.y += ev * xv.y;
        acc.z += ev * xv.z; acc.w += ev * xv.w;
    }
    float inv = 1.f / (z + 1e-16f);
    float4 r = make_float4(acc.x * inv, acc.y * inv, acc.z * inv, acc.w * inv);
    *(float4*)(qtraw + (size_t)g * H + lane * 4) = r;
    if (lane == 0) zout[g] = z;
}

// ---------- output head ----------
__global__ __launch_bounds__(256) void out_kernel(const float* __restrict__ X,
    const float* __restrict__ Wo, const float* __restrict__ bo,
    float* __restrict__ out, int N)
{
    int t = blockIdx.x * 256 + threadIdx.x;
    int n = t >> 5, lane = t & 31;
    if (n >= N) return;
    float4 xv = *(const float4*)(X + (size_t)n * H + lane * 4);
    float xa[4]; *(float4*)xa = xv;
    float p0 = 0.f, p1 = 0.f;
    #pragma unroll
    for (int j = 0; j < 4; ++j) {
        p0 += xa[j] * Wo[(lane*4 + j)*2 + 0];
        p1 += xa[j] * Wo[(lane*4 + j)*2 + 1];
    }
    #pragma unroll
    for (int m = 16; m >= 1; m >>= 1) { p0 += __shfl_xor(p0, m); p1 += __shfl_xor(p1, m); }
    if (lane == 0) {
        out[(size_t)n*2 + 0] = p0 + bo[0];
        out[(size_t)n*2 + 1] = p1 + bo[1];
    }
}

extern "C" void kernel_launch(void* const* d_in, const int* in_sizes, int n_in,
                              void* d_out, int out_size, void* d_ws, size_t ws_size,
                              hipStream_t stream)
{
    const float* x_tx      = (const float*)d_in[0];
    const float* x_cust    = (const float*)d_in[1];
    const int*   merch_ids = (const int*)d_in[2];
    const int*   e_ct_src  = (const int*)d_in[3];
    const int*   e_ct_dst  = (const int*)d_in[4];
    const int*   e_mt_src  = (const int*)d_in[5];
    const int*   e_mt_dst  = (const int*)d_in[6];
    const float* proj_tx_w   = (const float*)d_in[7];
    const float* proj_tx_b   = (const float*)d_in[8];
    const float* proj_cust_w = (const float*)d_in[9];
    const float* proj_cust_b = (const float*)d_in[10];
    const float* merch_emb   = (const float*)d_in[11];
    const float* kw = (const float*)d_in[12];
    const float* kb = (const float*)d_in[13];
    const float* qw = (const float*)d_in[14];
    const float* qb = (const float*)d_in[15];
    const float* vw = (const float*)d_in[16];
    const float* vb = (const float*)d_in[17];
    const float* aw = (const float*)d_in[18];
    const float* ab = (const float*)d_in[19];
    const float* skip  = (const float*)d_in[20];
    const float* a_rel = (const float*)d_in[21];
    const float* m_rel = (const float*)d_in[22];
    const float* p_rel = (const float*)d_in[23];
    const float* out_w = (const float*)d_in[24];
    const float* out_b = (const float*)d_in[25];
    (void)in_sizes; (void)n_in;

    const size_t nsz[3] = {NTX, NCU, NME};

    // workspace layout (floats, then ints, then bf16 weight planes) — ~264.7 MB of 256 MiB
    float* ws = (float*)d_ws;
    size_t off = 0;
    float* xs[3];  for (int t = 0; t < 3; ++t) { xs[t] = ws + off; off += nsz[t]*H; }
    float* agg0    = ws + off; off += (size_t)NTX * H;
    float* edgebuf = ws + off; off += EDGEBUF_FLOATS;   // qt/raw (in-place); agg1,agg2 aliased in tail
    float* cvec = ws + off; off += NTX;
    float* zbuf = ws + off; off += NTX;
    float* wc   = ws + off; off += 8 * WC_STRIDE;
    float* wkc  = ws + off; off += 8 * WKC_STRIDE;
    // int area
    int* ibase = (int*)(ws + off);
    const int rp_size[4] = {NTX + 1, NTX + 1, NCU + 1, NME + 1};
    int* rowp[4]; size_t ioff = 0;
    for (int r = 0; r < 4; ++r) { rowp[r] = ibase + ioff; ioff += rp_size[r]; }
    int* colix[4];
    for (int r = 0; r < 4; ++r) { colix[r] = ibase + ioff; ioff += NEDGE; }
    int* cursor = ibase + ioff; ioff += NTX;
    int* bsum   = ibase + ioff; ioff += 256;
    unsigned short* wt = (unsigned short*)(ibase + ioff);
    size_t needed_bytes = off * sizeof(float) + ioff * sizeof(int)
                        + (size_t)22 * 32768 * sizeof(unsigned short);

    float* agg[3] = { agg0, edgebuf + AGG1_OFF, edgebuf + AGG2_OFF };

    if (ws_size < needed_bytes) {
        fill_val<<<(out_size + 255) / 256, 256, 0, stream>>>(
            (float*)d_out, out_size, (float)(ws_size >> 20));
        return;
    }

    const int src_t[4] = {1, 2, 0, 0};
    const int dst_t[4] = {0, 0, 1, 2};
    const int* esrc[4] = {e_ct_src, e_mt_src, e_ct_dst, e_mt_dst};
    const int* edst[4] = {e_ct_dst, e_mt_dst, e_ct_src, e_mt_src};

    // ---- build CSR per relation (edges constant across layers) ----
    const int egrid256 = (NEDGE + 255) / 256;
    for (int r = 0; r < 4; ++r) {
        int ndt = (int)nsz[dst_t[r]];
        int nb = (ndt + SCAN_TILE - 1) / SCAN_TILE;
        zero_int<<<(ndt + 255) / 256, 256, 0, stream>>>(cursor, ndt);   // cursor as deg
        count_deg<<<egrid256, 256, 0, stream>>>(edst[r], cursor, NEDGE);
        scan1<<<nb, 256, 0, stream>>>(cursor, rowp[r], bsum, ndt);
        scan2<<<1, 64, 0, stream>>>(bsum, nb);
        scan3<<<nb, 256, 0, stream>>>(rowp[r], bsum, ndt, NEDGE);
        copy_int<<<(ndt + 255) / 256, 256, 0, stream>>>(cursor, rowp[r], ndt);
        fill_csr<<<egrid256, 256, 0, stream>>>(esrc[r], edst[r], cursor, colix[r], NEDGE);
    }

    // precombine weights (parallel), then bf16 hi/lo transposed planes
    combine1_par<<<64, 256, 0, stream>>>(kw, kb, vw, vb, a_rel, m_rel, wkc, wc);
    combine2_par<<<32, 256, 0, stream>>>(qw, qb, wkc, wc);
    wprep<<<22, 256, 0, stream>>>(wc, aw, wt);

    // input projections
    proj_kernel<16><<<(NTX + 1) / 2, 256, 0, stream>>>(x_tx, proj_tx_w, proj_tx_b, xs[0], NTX);
    proj_kernel<32><<<(NCU + 1) / 2, 256, 0, stream>>>(x_cust, proj_cust_w, proj_cust_b, xs[1], NCU);
    gather_rows<<<(NME * 32 + 255) / 256, 256, 0, stream>>>(merch_emb, merch_ids, xs[2], NME);

    for (int l = 0; l < NLAY; ++l) {
        for (int r = 0; r < 4; ++r) {
            int st = src_t[r], dt = dst_t[r];
            int ndt = (int)nsz[dt];
            int combo = l * 4 + r;
            const float* QWc  = wc + (size_t)combo * WC_STRIDE;
            const float* qbc  = QWc + 32768;
            const float* bvc  = QWc + 32896;
            const float* gvec = QWc + 33024;
            const float* gsc  = QWc + 33152;
            const unsigned short* wtQ = wt + (size_t)(combo * 2 + 0) * 32768;
            const unsigned short* wtV = wt + (size_t)(combo * 2 + 1) * 32768;
            int grid = (ndt + 63) / 64;

            // qt = xs[dt] @ QWc + qbc  (into edgebuf); fused cvec
            mfma_gemm<0, 1><<<grid, 256, 0, stream>>>(
                xs[dt], wtQ, qbc, edgebuf, ndt, nullptr, nullptr, nullptr,
                gvec, gsc, cvec);
            // fused score+softmax+aggregate, in place over qt
            gather_agg<<<(ndt + 7) / 8, 256, 0, stream>>>(
                rowp[r], colix[r], edgebuf, xs[st], cvec, p_rel, combo, zbuf, ndt);
            // agg[dt] = / += raw @ WVc + gate*bvc   (r==1 is the only second-accumulate)
            if (r == 1)
                mfma_gemm<2, 0><<<grid, 256, 0, stream>>>(
                    edgebuf, wtV, bvc, agg[dt], ndt, nullptr, nullptr, zbuf,
                    nullptr, nullptr, nullptr);
            else
                mfma_gemm<3, 0><<<grid, 256, 0, stream>>>(
                    edgebuf, wtV, bvc, agg[dt], ndt, nullptr, nullptr, zbuf,
                    nullptr, nullptr, nullptr);
        }

        // update: xs = relu(beta*(gelu(agg)@aw + ab) + (1-beta)*xs)
        for (int t = 0; t < 3; ++t)
            mfma_gemm<1, 0><<<(int)((nsz[t] + 63) / 64), 256, 0, stream>>>(
                agg[t], wt + (size_t)(16 + l*3 + t) * 32768,
                ab + (size_t)(l*3 + t)*H, xs[t], (int)nsz[t],
                xs[t], skip + l*3 + t, nullptr, nullptr, nullptr, nullptr);
    }

    out_kernel<<<(NTX * 32 + 255) / 256, 256, 0, stream>>>(xs[0], out_w, out_b, (float*)d_out, NTX);
}

// Round 7
// 1236.316 us; speedup vs baseline: 3.2643x; 1.0787x over previous
//
#include <hip/hip_runtime.h>
#include <math.h>

#define H 128
#define NTX 150000
#define NCU 40000
#define NME 10000
#define NEDGE 150000
#define NLAY 2
#define WC_STRIDE 33280     // per (l,r): QWc@0, WVc@16384, qbc@32768, bvc@32896, gvec@33024, gsc@33152
#define WKC_STRIDE 16640    // per (l,r): WKc@0, bkc@16384
#define BUF_FLOATS 19200000       // NTX*H (edgebuf and bufB each)
#define AGG2_OFF 5120000          // bufB offset for agg[2] region (after NCU*H)
#define SCAN_TILE 2048

typedef short s8v __attribute__((ext_vector_type(8)));
typedef float f32x4 __attribute__((ext_vector_type(4)));

__device__ __forceinline__ float gelu_exact(float x) {
    return 0.5f * x * (1.0f + erff(x * 0.70710678118654752f));
}
__device__ __forceinline__ unsigned short f2bf(float x) {   // RNE f32->bf16 bits
    unsigned u = __float_as_uint(x);
    return (unsigned short)((u + 0x7FFFu + ((u >> 16) & 1u)) >> 16);
}
__device__ __forceinline__ float bf2f(unsigned short b) {
    return __uint_as_float(((unsigned)b) << 16);
}

// ---------- fills ----------
__global__ __launch_bounds__(256) void fill_val(float* p, int n, float v) {
    int i = blockIdx.x * 256 + threadIdx.x;
    if (i < n) p[i] = v;
}
__global__ __launch_bounds__(256) void zero_int(int* p, int n) {
    int i = blockIdx.x * 256 + threadIdx.x;
    if (i < n) p[i] = 0;
}
__global__ __launch_bounds__(256) void copy_int(int* d, const int* s, int n) {
    int i = blockIdx.x * 256 + threadIdx.x;
    if (i < n) d[i] = s[i];
}

// ---------- CSR build ----------
__global__ __launch_bounds__(256) void count_deg(const int* __restrict__ dst,
    int* __restrict__ deg, int E)
{
    int e = blockIdx.x * 256 + threadIdx.x;
    if (e < E) atomicAdd(&deg[dst[e]], 1);
}
__global__ __launch_bounds__(256) void scan1(const int* __restrict__ deg,
    int* __restrict__ out, int* __restrict__ bsum, int n)
{
    __shared__ int ts[256];
    int tid = threadIdx.x;
    int base = blockIdx.x * SCAN_TILE + tid * 8;
    int v[8], pre[8], s = 0;
    #pragma unroll
    for (int j = 0; j < 8; ++j) {
        int idx = base + j;
        v[j] = (idx < n) ? deg[idx] : 0;
        pre[j] = s; s += v[j];
    }
    ts[tid] = s;
    __syncthreads();
    for (int off = 1; off < 256; off <<= 1) {
        int t = (tid >= off) ? ts[tid - off] : 0;
        __syncthreads();
        ts[tid] += t;
        __syncthreads();
    }
    int excl = ts[tid] - s;
    #pragma unroll
    for (int j = 0; j < 8; ++j)
        if (base + j < n) out[base + j] = excl + pre[j];
    if (tid == 255) bsum[blockIdx.x] = ts[255];
}
__global__ __launch_bounds__(64) void scan2(int* __restrict__ bsum, int nb) {
    if (threadIdx.x == 0 && blockIdx.x == 0) {
        int run = 0;
        for (int i = 0; i < nb; ++i) { int t = bsum[i]; bsum[i] = run; run += t; }
    }
}
__global__ __launch_bounds__(256) void scan3(int* __restrict__ out,
    const int* __restrict__ bsum, int n, int total)
{
    int base = blockIdx.x * SCAN_TILE;
    int add = bsum[blockIdx.x];
    for (int j = threadIdx.x; j < SCAN_TILE; j += 256) {
        int k = base + j;
        if (k < n) out[k] += add;
    }
    if (blockIdx.x == 0 && threadIdx.x == 0) out[n] = total;
}
__global__ __launch_bounds__(256) void fill_csr(const int* __restrict__ src,
    const int* __restrict__ dst, int* __restrict__ cursor, int* __restrict__ col, int E)
{
    int e = blockIdx.x * 256 + threadIdx.x;
    if (e >= E) return;
    int pos = atomicAdd(&cursor[dst[e]], 1);
    col[pos] = src[e];
}

// ---------- vectorized projection: Y = X(NxK) @ W(KxH) + b, 8 nodes/block ----------
template<int K>
__global__ __launch_bounds__(256) void proj_kernel(const float* __restrict__ X,
    const float* __restrict__ W, const float* __restrict__ B,
    float* __restrict__ Y, int N)
{
    __shared__ float Wl[K][128];
    __shared__ float Bl[128];
    int tid = threadIdx.x;
    for (int i = tid; i < K * 128; i += 256) Wl[i >> 7][i & 127] = W[i];
    if (tid < 128) Bl[tid] = B[tid];
    __syncthreads();
    int ng = tid >> 5, lane = tid & 31;
    int n = blockIdx.x * 8 + ng;
    if (n >= N) return;
    const float* xr = X + (size_t)n * K;
    float xa[K];
    #pragma unroll
    for (int k4 = 0; k4 < K / 4; ++k4)
        *(float4*)&xa[k4 * 4] = *(const float4*)(xr + k4 * 4);
    int c0 = lane * 4;
    float4 acc = *(const float4*)&Bl[c0];
    #pragma unroll
    for (int k = 0; k < K; ++k) {
        float4 w = *(const float4*)&Wl[k][c0];
        acc.x += xa[k] * w.x; acc.y += xa[k] * w.y;
        acc.z += xa[k] * w.z; acc.w += xa[k] * w.w;
    }
    *(float4*)(Y + (size_t)n * H + c0) = acc;
}

// ---------- gather rows ----------
__global__ __launch_bounds__(256) void gather_rows(const float* __restrict__ src,
    const int* __restrict__ ids, float* __restrict__ dstp, int N)
{
    int t = blockIdx.x * 256 + threadIdx.x;
    if (t >= N * 32) return;
    int n = t >> 5, c4 = t & 31;
    int sid = ids[n];
    ((float4*)dstp)[(size_t)n * 32 + c4] = ((const float4*)src)[(size_t)sid * 32 + c4];
}

// ---------- combine stage 1 (parallel, 64 blocks) ----------
__global__ __launch_bounds__(256) void combine1_par(const float* __restrict__ kw,
    const float* __restrict__ kb, const float* __restrict__ vw, const float* __restrict__ vb,
    const float* __restrict__ a_rel, const float* __restrict__ m_rel,
    float* __restrict__ wkc, float* __restrict__ wc)
{
    __shared__ float Rs[64][132];
    int b = blockIdx.x;
    int combo = b >> 3;
    int pass  = (b >> 2) & 1;
    int slice = b & 3;
    int l = combo >> 2, r = combo & 3;
    const int src_t[4] = {1, 2, 0, 0};
    int st = src_t[r];
    const float* Ap = (pass ? vw : kw) + (size_t)(l*3 + st) * H * H;
    const float* Rp = (pass ? m_rel : a_rel) + (size_t)combo * H * H;
    float* Out = pass ? (wc + (size_t)combo * WC_STRIDE + 16384)
                      : (wkc + (size_t)combo * WKC_STRIDE);

    int tid = threadIdx.x;
    int i = slice * 32 + (tid >> 3);
    int jb = tid & 7;
    float acc[16];
    #pragma unroll
    for (int j = 0; j < 16; ++j) acc[j] = 0.f;

    for (int half = 0; half < 2; ++half) {
        __syncthreads();
        for (int idx = tid; idx < 64 * 128; idx += 256)
            Rs[idx >> 7][idx & 127] = Rp[(half * 64 + (idx >> 7)) * H + (idx & 127)];
        __syncthreads();
        for (int k = 0; k < 64; ++k) {
            float a = Ap[i * H + half * 64 + k];
            #pragma unroll
            for (int j = 0; j < 16; ++j) acc[j] += a * Rs[k][jb + j * 8];
        }
    }
    #pragma unroll
    for (int j = 0; j < 16; ++j) Out[i * H + jb + j * 8] = acc[j];

    if (pass == 0 && slice == 0) {
        const float* Akb = kb + (size_t)(l*3 + st) * H;
        const float* Avb = vb + (size_t)(l*3 + st) * H;
        const float* Rk = a_rel + (size_t)combo * H * H;
        const float* Rv = m_rel + (size_t)combo * H * H;
        float* bkc = wkc + (size_t)combo * WKC_STRIDE + H * H;
        float* bvc = wc + (size_t)combo * WC_STRIDE + 32896;
        if (tid < 128) {
            float s = 0.f;
            for (int k = 0; k < H; ++k) s += Akb[k] * Rk[k * H + tid];
            bkc[tid] = s;
        } else {
            int c = tid - 128;
            float s = 0.f;
            for (int k = 0; k < H; ++k) s += Avb[k] * Rv[k * H + c];
            bvc[c] = s;
        }
    }
}

// ---------- combine stage 2 (parallel, 32 blocks): QWc = qw[dt] @ WKc^T ----------
__global__ __launch_bounds__(256) void combine2_par(const float* __restrict__ qw,
    const float* __restrict__ qb, const float* __restrict__ wkc, float* __restrict__ wc)
{
    __shared__ float BsT[64][133];
    int b = blockIdx.x;
    int combo = b >> 2;
    int slice = b & 3;
    int l = combo >> 2, r = combo & 3;
    const int dst_t[4] = {0, 0, 1, 2};
    int dt = dst_t[r];
    const float* Q  = qw + (size_t)(l*3 + dt) * H * H;
    const float* Qb = qb + (size_t)(l*3 + dt) * H;
    const float* WKc = wkc + (size_t)combo * WKC_STRIDE;
    const float* bkc = WKc + H * H;
    float* QWc = wc + (size_t)combo * WC_STRIDE;

    int tid = threadIdx.x;
    int i = slice * 32 + (tid >> 3);
    int jb = tid & 7;
    float acc[16];
    #pragma unroll
    for (int j = 0; j < 16; ++j) acc[j] = 0.f;

    for (int half = 0; half < 2; ++half) {
        __syncthreads();
        for (int idx = tid; idx < 64 * 128; idx += 256) {
            int j = idx >> 6, k = idx & 63;
            BsT[k][j] = WKc[j * H + half * 64 + k];
        }
        __syncthreads();
        for (int k = 0; k < 64; ++k) {
            float a = Q[i * H + half * 64 + k];
            #pragma unroll
            for (int j = 0; j < 16; ++j) acc[j] += a * BsT[k][jb + j * 8];
        }
    }
    #pragma unroll
    for (int j = 0; j < 16; ++j) QWc[i * H + jb + j * 8] = acc[j];

    if (slice == 0) {
        float* qbc  = wc + (size_t)combo * WC_STRIDE + 32768;
        float* gvec = wc + (size_t)combo * WC_STRIDE + 33024;
        float* gsc  = wc + (size_t)combo * WC_STRIDE + 33152;
        if (tid < 128) {
            float s = 0.f;
            for (int k = 0; k < H; ++k) s += Qb[k] * WKc[tid * H + k];
            qbc[tid] = s;
            if (tid == 0) {
                float g = 0.f;
                for (int k = 0; k < H; ++k) g += Qb[k] * bkc[k];
                gsc[0] = g;
            }
        } else {
            int c = tid - 128;
            float s = 0.f;
            for (int k = 0; k < H; ++k) s += Q[c * H + k] * bkc[k];
            gvec[c] = s;
        }
    }
}

// ---------- weight prep: transpose + split f32 -> bf16 hi/lo, layout [j][k] ----------
__global__ __launch_bounds__(256) void wprep(const float* __restrict__ wc,
    const float* __restrict__ aw, unsigned short* __restrict__ wt)
{
    int b = blockIdx.x;
    const float* src = (b < 16)
        ? wc + (size_t)(b >> 1) * WC_STRIDE + ((b & 1) ? 16384 : 0)
        : aw + (size_t)(b - 16) * 16384;
    unsigned short* hi = wt + (size_t)b * 32768;
    unsigned short* lo = hi + 16384;
    for (int idx = threadIdx.x; idx < 16384; idx += 256) {
        int k = idx >> 7, j = idx & 127;
        float w = src[idx];
        unsigned short h = f2bf(w);
        hi[j * 128 + k] = h;
        lo[j * 128 + k] = f2bf(w - bf2f(h));
    }
}

// ---------- staging helper: f32 row tile -> split-bf16 LDS planes ----------
#define STAGE_TILE(SRC, GELU)                                               \
    _Pragma("unroll")                                                       \
    for (int i = 0; i < 8; ++i) {                                           \
        int u = tid + i * 256;                                              \
        int n = u >> 5, c4 = u & 31;                                        \
        int gn = nb + n;                                                    \
        float4 v = make_float4(0.f, 0.f, 0.f, 0.f);                         \
        if (gn < N) v = *(const float4*)((SRC) + (size_t)gn * H + c4 * 4);  \
        if (GELU) {                                                         \
            v.x = gelu_exact(v.x); v.y = gelu_exact(v.y);                   \
            v.z = gelu_exact(v.z); v.w = gelu_exact(v.w);                   \
        }                                                                   \
        ushort4 h, lo;                                                      \
        h.x = f2bf(v.x); lo.x = f2bf(v.x - bf2f(h.x));                      \
        h.y = f2bf(v.y); lo.y = f2bf(v.y - bf2f(h.y));                      \
        h.z = f2bf(v.z); lo.z = f2bf(v.z - bf2f(h.z));                      \
        h.w = f2bf(v.w); lo.w = f2bf(v.w - bf2f(h.w));                      \
        *(ushort4*)&lds[0][n][c4 * 4] = h;                                  \
        *(ushort4*)&lds[1][n][c4 * 4] = lo;                                 \
    }

#define LOAD_BFRAG(WT)                                                      \
    _Pragma("unroll")                                                       \
    for (int n = 0; n < 2; ++n) {                                           \
        int j = col0 + n * 16 + l15;                                        \
        _Pragma("unroll")                                                   \
        for (int kb = 0; kb < 4; ++kb) {                                    \
            bhi[n][kb] = *(const s8v*)((WT) + (size_t)j * 128 + kb * 32 + kg * 8);          \
            blo[n][kb] = *(const s8v*)((WT) + 16384 + (size_t)j * 128 + kb * 32 + kg * 8);  \
        }                                                                   \
    }

#define MFMA_PASS()                                                         \
    _Pragma("unroll")                                                       \
    for (int m = 0; m < 4; ++m) {                                           \
        int row = m * 16 + l15;                                             \
        _Pragma("unroll")                                                   \
        for (int kb = 0; kb < 4; ++kb) {                                    \
            s8v ah = *(const s8v*)&lds[0][row][kb * 32 + kg * 8];           \
            s8v al = *(const s8v*)&lds[1][row][kb * 32 + kg * 8];           \
            _Pragma("unroll")                                               \
            for (int n = 0; n < 2; ++n) {                                   \
                acc[m][n] = __builtin_amdgcn_mfma_f32_16x16x32_bf16(ah, bhi[n][kb], acc[m][n], 0, 0, 0); \
                acc[m][n] = __builtin_amdgcn_mfma_f32_16x16x32_bf16(al, bhi[n][kb], acc[m][n], 0, 0, 0); \
                acc[m][n] = __builtin_amdgcn_mfma_f32_16x16x32_bf16(ah, blo[n][kb], acc[m][n], 0, 0, 0); \
            }                                                               \
        }                                                                   \
    }

// ---------- MFMA split-bf16 GEMM (single weight set) ----------
// MODE 0: Y = X@W + B   (+ fused cvec when HASCV)
// MODE 1: Y = relu(beta*(gelu(X)@W + B) + (1-beta)*Xold)
// MODE 3: Y = X@W + gate*B    (gate = zb[n]>0; X==Y in-place allowed)
template<int MODE, int HASCV>
__global__ __launch_bounds__(256) void mfma_gemm(const float* __restrict__ X,
    const unsigned short* __restrict__ Wt, const float* __restrict__ Bias,
    float* __restrict__ Y, int N, const float* __restrict__ Xold,
    const float* __restrict__ skipP, const float* __restrict__ zb,
    const float* __restrict__ gvecp, const float* __restrict__ gscp,
    float* __restrict__ cvecout)
{
    __shared__ unsigned short lds[2][64][136];
    __shared__ float cacc[64];
    int tid = threadIdx.x;
    int nb = blockIdx.x * 64;

    if (HASCV) {
        if (tid < 64) cacc[tid] = 0.f;
        __syncthreads();
    }
    if (HASCV) {
        #pragma unroll
        for (int i = 0; i < 8; ++i) {
            int u = tid + i * 256;
            int n = u >> 5, c4 = u & 31;
            int gn = nb + n;
            float4 v = make_float4(0.f, 0.f, 0.f, 0.f);
            if (gn < N) v = *(const float4*)(X + (size_t)gn * H + c4 * 4);
            float4 gv = *(const float4*)(gvecp + c4 * 4);
            atomicAdd(&cacc[n], v.x*gv.x + v.y*gv.y + v.z*gv.z + v.w*gv.w);
            ushort4 h, lo;
            h.x = f2bf(v.x); lo.x = f2bf(v.x - bf2f(h.x));
            h.y = f2bf(v.y); lo.y = f2bf(v.y - bf2f(h.y));
            h.z = f2bf(v.z); lo.z = f2bf(v.z - bf2f(h.z));
            h.w = f2bf(v.w); lo.w = f2bf(v.w - bf2f(h.w));
            *(ushort4*)&lds[0][n][c4 * 4] = h;
            *(ushort4*)&lds[1][n][c4 * 4] = lo;
        }
    } else {
        STAGE_TILE(X, MODE == 1)
    }
    __syncthreads();
    if (HASCV) {
        if (tid < 64 && nb + tid < N) cvecout[nb + tid] = cacc[tid] + gscp[0];
    }

    int wid = tid >> 6, lane = tid & 63;
    int l15 = lane & 15, kg = lane >> 4;
    int col0 = wid * 32;

    s8v bhi[2][4], blo[2][4];
    LOAD_BFRAG(Wt)

    f32x4 acc[4][2];
    #pragma unroll
    for (int m = 0; m < 4; ++m)
        #pragma unroll
        for (int n = 0; n < 2; ++n)
            acc[m][n] = (f32x4){0.f, 0.f, 0.f, 0.f};

    MFMA_PASS()

    float beta = 0.f, omb = 0.f;
    if (MODE == 1) {
        float s = *skipP;
        beta = 1.f / (1.f + expf(-s));
        omb = 1.f - beta;
    }
    float bias0 = Bias[col0 + l15];
    float bias1 = Bias[col0 + 16 + l15];

    #pragma unroll
    for (int m = 0; m < 4; ++m) {
        #pragma unroll
        for (int r = 0; r < 4; ++r) {
            int grow = nb + m * 16 + kg * 4 + r;
            if (grow < N) {
                float gate = 1.f;
                if (MODE == 3) gate = (zb[grow] > 0.f) ? 1.f : 0.f;
                #pragma unroll
                for (int n = 0; n < 2; ++n) {
                    int col = col0 + n * 16 + l15;
                    float val = acc[m][n][r];
                    float bs = n ? bias1 : bias0;
                    size_t yi = (size_t)grow * H + col;
                    if (MODE == 0) {
                        Y[yi] = val + bs;
                    } else if (MODE == 3) {
                        Y[yi] = val + gate * bs;
                    } else {
                        float o = val + bs;
                        float xo = Xold[yi];
                        Y[yi] = fmaxf(beta * o + omb * xo, 0.f);
                    }
                }
            }
        }
    }
}

// ---------- fused dual qt GEMM: Y0 = X@W0 + b0, Y1 = X@W1 + b1, + both cvecs ----------
__global__ __launch_bounds__(256) void mfma_gemm2q(const float* __restrict__ X,
    const unsigned short* __restrict__ Wt0, const unsigned short* __restrict__ Wt1,
    const float* __restrict__ b0, const float* __restrict__ b1,
    float* __restrict__ Y0, float* __restrict__ Y1, int N,
    const float* __restrict__ gv0, const float* __restrict__ gs0, float* __restrict__ cv0,
    const float* __restrict__ gv1, const float* __restrict__ gs1, float* __restrict__ cv1)
{
    __shared__ unsigned short lds[2][64][136];
    __shared__ float cacc0[64], cacc1[64];
    int tid = threadIdx.x;
    int nb = blockIdx.x * 64;
    if (tid < 64) { cacc0[tid] = 0.f; cacc1[tid] = 0.f; }
    __syncthreads();

    #pragma unroll
    for (int i = 0; i < 8; ++i) {
        int u = tid + i * 256;
        int n = u >> 5, c4 = u & 31;
        int gn = nb + n;
        float4 v = make_float4(0.f, 0.f, 0.f, 0.f);
        if (gn < N) v = *(const float4*)(X + (size_t)gn * H + c4 * 4);
        float4 g0 = *(const float4*)(gv0 + c4 * 4);
        float4 g1 = *(const float4*)(gv1 + c4 * 4);
        atomicAdd(&cacc0[n], v.x*g0.x + v.y*g0.y + v.z*g0.z + v.w*g0.w);
        atomicAdd(&cacc1[n], v.x*g1.x + v.y*g1.y + v.z*g1.z + v.w*g1.w);
        ushort4 h, lo;
        h.x = f2bf(v.x); lo.x = f2bf(v.x - bf2f(h.x));
        h.y = f2bf(v.y); lo.y = f2bf(v.y - bf2f(h.y));
        h.z = f2bf(v.z); lo.z = f2bf(v.z - bf2f(h.z));
        h.w = f2bf(v.w); lo.w = f2bf(v.w - bf2f(h.w));
        *(ushort4*)&lds[0][n][c4 * 4] = h;
        *(ushort4*)&lds[1][n][c4 * 4] = lo;
    }
    __syncthreads();
    if (tid < 64 && nb + tid < N) {
        cv0[nb + tid] = cacc0[tid] + gs0[0];
        cv1[nb + tid] = cacc1[tid] + gs1[0];
    }

    int wid = tid >> 6, lane = tid & 63;
    int l15 = lane & 15, kg = lane >> 4;
    int col0 = wid * 32;

    #pragma unroll
    for (int set = 0; set < 2; ++set) {
        const unsigned short* Wt = set ? Wt1 : Wt0;
        const float* Bias = set ? b1 : b0;
        float* Y = set ? Y1 : Y0;

        s8v bhi[2][4], blo[2][4];
        LOAD_BFRAG(Wt)

        f32x4 acc[4][2];
        #pragma unroll
        for (int m = 0; m < 4; ++m)
            #pragma unroll
            for (int n = 0; n < 2; ++n)
                acc[m][n] = (f32x4){0.f, 0.f, 0.f, 0.f};

        MFMA_PASS()

        float bias0 = Bias[col0 + l15];
        float bias1 = Bias[col0 + 16 + l15];
        #pragma unroll
        for (int m = 0; m < 4; ++m) {
            #pragma unroll
            for (int r = 0; r < 4; ++r) {
                int grow = nb + m * 16 + kg * 4 + r;
                if (grow < N) {
                    #pragma unroll
                    for (int n = 0; n < 2; ++n) {
                        int col = col0 + n * 16 + l15;
                        Y[(size_t)grow * H + col] = acc[m][n][r] + (n ? bias1 : bias0);
                    }
                }
            }
        }
    }
}

// ---------- fused K=256 V-GEMM: A0 <- A0@W0 + A1@W1 + gate0*b0 + gate1*b1 (in-place) ----------
__global__ __launch_bounds__(256) void mfma_gemmV2(float* __restrict__ A0,
    const float* __restrict__ A1,
    const unsigned short* __restrict__ Wt0, const unsigned short* __restrict__ Wt1,
    const float* __restrict__ bv0, const float* __restrict__ bv1,
    const float* __restrict__ z0, const float* __restrict__ z1, int N)
{
    __shared__ unsigned short lds[2][64][136];
    int tid = threadIdx.x;
    int nb = blockIdx.x * 64;
    int wid = tid >> 6, lane = tid & 63;
    int l15 = lane & 15, kg = lane >> 4;
    int col0 = wid * 32;

    f32x4 acc[4][2];
    #pragma unroll
    for (int m = 0; m < 4; ++m)
        #pragma unroll
        for (int n = 0; n < 2; ++n)
            acc[m][n] = (f32x4){0.f, 0.f, 0.f, 0.f};

    #pragma unroll
    for (int half = 0; half < 2; ++half) {
        const float* A = half ? A1 : A0;
        const unsigned short* Wt = half ? Wt1 : Wt0;
        if (half) __syncthreads();   // prior LDS reads done before restage
        STAGE_TILE(A, 0)
        __syncthreads();
        s8v bhi[2][4], blo[2][4];
        LOAD_BFRAG(Wt)
        MFMA_PASS()
    }

    float b00 = bv0[col0 + l15],  b01 = bv0[col0 + 16 + l15];
    float b10 = bv1[col0 + l15],  b11 = bv1[col0 + 16 + l15];

    #pragma unroll
    for (int m = 0; m < 4; ++m) {
        #pragma unroll
        for (int r = 0; r < 4; ++r) {
            int grow = nb + m * 16 + kg * 4 + r;
            if (grow < N) {
                float g0 = (z0[grow] > 0.f) ? 1.f : 0.f;
                float g1 = (z1[grow] > 0.f) ? 1.f : 0.f;
                #pragma unroll
                for (int n = 0; n < 2; ++n) {
                    int col = col0 + n * 16 + l15;
                    float bs = n ? (g0 * b01 + g1 * b11) : (g0 * b00 + g1 * b10);
                    A0[(size_t)grow * H + col] = acc[m][n][r] + bs;
                }
            }
        }
    }
}

// ---------- fused edge phase: per dst node, single pass over CSR ----------
__global__ __launch_bounds__(256) void gather_agg(const int* __restrict__ row_ptr,
    const int* __restrict__ col_idx, float* __restrict__ qtraw,
    const float* __restrict__ xsrc, const float* __restrict__ cvec,
    const float* __restrict__ prel, int ridx, float* __restrict__ zout, int ndt)
{
    int g = blockIdx.x * 8 + (threadIdx.x >> 5);
    int lane = threadIdx.x & 31;
    if (g >= ndt) return;
    float4 qv = *(const float4*)(qtraw + (size_t)g * H + lane * 4);
    float scale = prel[ridx] * 0.08838834764831843f;   // 1/sqrt(128)
    float cv = cvec[g];
    int beg = row_ptr[g], end = row_ptr[g + 1];
    float4 acc = make_float4(0.f, 0.f, 0.f, 0.f);
    float z = 0.f;
    for (int i = beg; i < end; ++i) {
        int s = col_idx[i];
        float4 xv = *(const float4*)(xsrc + (size_t)s * H + lane * 4);
        float p = qv.x*xv.x + qv.y*xv.y + qv.z*xv.z + qv.w*xv.w;
        #pragma unroll
        for (int m = 16; m >= 1; m >>= 1) p += __shfl_xor(p, m);
        float ev = expf((p + cv) * scale);
        z += ev;
        acc.x += ev * xv.x; acc.y += ev * xv.y;
        acc.z += ev * xv.z; acc.w += ev * xv.w;
    }
    float inv = 1.f / (z + 1e-16f);
    float4 r = make_float4(acc.x * inv, acc.y * inv, acc.z * inv, acc.w * inv);
    *(float4*)(qtraw + (size_t)g * H + lane * 4) = r;
    if (lane == 0) zout[g] = z;
}

// ---------- output head ----------
__global__ __launch_bounds__(256) void out_kernel(const float* __restrict__ X,
    const float* __restrict__ Wo, const float* __restrict__ bo,
    float* __restrict__ out, int N)
{
    int t = blockIdx.x * 256 + threadIdx.x;
    int n = t >> 5, lane = t & 31;
    if (n >= N) return;
    float4 xv = *(const float4*)(X + (size_t)n * H + lane * 4);
    float xa[4]; *(float4*)xa = xv;
    float p0 = 0.f, p1 = 0.f;
    #pragma unroll
    for (int j = 0; j < 4; ++j) {
        p0 += xa[j] * Wo[(lane*4 + j)*2 + 0];
        p1 += xa[j] * Wo[(lane*4 + j)*2 + 1];
    }
    #pragma unroll
    for (int m = 16; m >= 1; m >>= 1) { p0 += __shfl_xor(p0, m); p1 += __shfl_xor(p1, m); }
    if (lane == 0) {
        out[(size_t)n*2 + 0] = p0 + bo[0];
        out[(size_t)n*2 + 1] = p1 + bo[1];
    }
}

extern "C" void kernel_launch(void* const* d_in, const int* in_sizes, int n_in,
                              void* d_out, int out_size, void* d_ws, size_t ws_size,
                              hipStream_t stream)
{
    const float* x_tx      = (const float*)d_in[0];
    const float* x_cust    = (const float*)d_in[1];
    const int*   merch_ids = (const int*)d_in[2];
    const int*   e_ct_src  = (const int*)d_in[3];
    const int*   e_ct_dst  = (const int*)d_in[4];
    const int*   e_mt_src  = (const int*)d_in[5];
    const int*   e_mt_dst  = (const int*)d_in[6];
    const float* proj_tx_w   = (const float*)d_in[7];
    const float* proj_tx_b   = (const float*)d_in[8];
    const float* proj_cust_w = (const float*)d_in[9];
    const float* proj_cust_b = (const float*)d_in[10];
    const float* merch_emb   = (const float*)d_in[11];
    const float* kw = (const float*)d_in[12];
    const float* kb = (const float*)d_in[13];
    const float* qw = (const float*)d_in[14];
    const float* qb = (const float*)d_in[15];
    const float* vw = (const float*)d_in[16];
    const float* vb = (const float*)d_in[17];
    const float* aw = (const float*)d_in[18];
    const float* ab = (const float*)d_in[19];
    const float* skip  = (const float*)d_in[20];
    const float* a_rel = (const float*)d_in[21];
    const float* m_rel = (const float*)d_in[22];
    const float* p_rel = (const float*)d_in[23];
    const float* out_w = (const float*)d_in[24];
    const float* out_b = (const float*)d_in[25];
    (void)in_sizes; (void)n_in;

    const size_t nsz[3] = {NTX, NCU, NME};

    // workspace layout — ~266 MB of 268.4 MB (256 MiB) budget
    float* ws = (float*)d_ws;
    size_t off = 0;
    float* xs[3];  for (int t = 0; t < 3; ++t) { xs[t] = ws + off; off += nsz[t]*H; }
    float* bufB    = ws + off; off += BUF_FLOATS;   // qt_r1/raw_r1; later agg1 @0, agg2 @AGG2_OFF
    float* edgebuf = ws + off; off += BUF_FLOATS;   // qt_r0/raw_r0 -> agg0 (in-place V2)
    float* cvec0 = ws + off; off += NTX;
    float* cvec1 = ws + off; off += NTX;
    float* zbuf0 = ws + off; off += NTX;
    float* zbuf1 = ws + off; off += NTX;
    float* wc   = ws + off; off += 8 * WC_STRIDE;
    float* wkc  = ws + off; off += 8 * WKC_STRIDE;
    int* ibase = (int*)(ws + off);
    const int rp_size[4] = {NTX + 1, NTX + 1, NCU + 1, NME + 1};
    int* rowp[4]; size_t ioff = 0;
    for (int r = 0; r < 4; ++r) { rowp[r] = ibase + ioff; ioff += rp_size[r]; }
    int* colix[4];
    for (int r = 0; r < 4; ++r) { colix[r] = ibase + ioff; ioff += NEDGE; }
    int* cursor = ibase + ioff; ioff += NTX;
    int* bsum   = ibase + ioff; ioff += 256;
    unsigned short* wt = (unsigned short*)(ibase + ioff);
    size_t needed_bytes = off * sizeof(float) + ioff * sizeof(int)
                        + (size_t)22 * 32768 * sizeof(unsigned short);

    if (ws_size < needed_bytes) {
        fill_val<<<(out_size + 255) / 256, 256, 0, stream>>>(
            (float*)d_out, out_size, (float)(ws_size >> 20));
        return;
    }

    const int src_t[4] = {1, 2, 0, 0};
    const int dst_t[4] = {0, 0, 1, 2};
    const int* esrc[4] = {e_ct_src, e_mt_src, e_ct_dst, e_mt_dst};
    const int* edst[4] = {e_ct_dst, e_mt_dst, e_ct_src, e_mt_src};

    // ---- build CSR per relation (edges constant across layers) ----
    const int egrid256 = (NEDGE + 255) / 256;
    for (int r = 0; r < 4; ++r) {
        int ndt = (int)nsz[dst_t[r]];
        int nb = (ndt + SCAN_TILE - 1) / SCAN_TILE;
        zero_int<<<(ndt + 255) / 256, 256, 0, stream>>>(cursor, ndt);
        count_deg<<<egrid256, 256, 0, stream>>>(edst[r], cursor, NEDGE);
        scan1<<<nb, 256, 0, stream>>>(cursor, rowp[r], bsum, ndt);
        scan2<<<1, 64, 0, stream>>>(bsum, nb);
        scan3<<<nb, 256, 0, stream>>>(rowp[r], bsum, ndt, NEDGE);
        copy_int<<<(ndt + 255) / 256, 256, 0, stream>>>(cursor, rowp[r], ndt);
        fill_csr<<<egrid256, 256, 0, stream>>>(esrc[r], edst[r], cursor, colix[r], NEDGE);
    }

    // precombine weights, then bf16 hi/lo transposed planes
    combine1_par<<<64, 256, 0, stream>>>(kw, kb, vw, vb, a_rel, m_rel, wkc, wc);
    combine2_par<<<32, 256, 0, stream>>>(qw, qb, wkc, wc);
    wprep<<<22, 256, 0, stream>>>(wc, aw, wt);

    // input projections
    proj_kernel<16><<<(NTX + 7) / 8, 256, 0, stream>>>(x_tx, proj_tx_w, proj_tx_b, xs[0], NTX);
    proj_kernel<32><<<(NCU + 7) / 8, 256, 0, stream>>>(x_cust, proj_cust_w, proj_cust_b, xs[1], NCU);
    gather_rows<<<(NME * 32 + 255) / 256, 256, 0, stream>>>(merch_emb, merch_ids, xs[2], NME);

    float* aggT[3] = { edgebuf, bufB, bufB + AGG2_OFF };

    for (int l = 0; l < NLAY; ++l) {
        int c0 = l * 4 + 0, c1 = l * 4 + 1;
        const float* W0 = wc + (size_t)c0 * WC_STRIDE;
        const float* W1 = wc + (size_t)c1 * WC_STRIDE;

        // fused r0+r1 qt (dt = tx for both): X read once
        mfma_gemm2q<<<(NTX + 63) / 64, 256, 0, stream>>>(
            xs[0], wt + (size_t)(c0*2) * 32768, wt + (size_t)(c1*2) * 32768,
            W0 + 32768, W1 + 32768, edgebuf, bufB, NTX,
            W0 + 33024, W0 + 33152, cvec0, W1 + 33024, W1 + 33152, cvec1);
        gather_agg<<<(NTX + 7) / 8, 256, 0, stream>>>(
            rowp[0], colix[0], edgebuf, xs[1], cvec0, p_rel, c0, zbuf0, NTX);
        gather_agg<<<(NTX + 7) / 8, 256, 0, stream>>>(
            rowp[1], colix[1], bufB, xs[2], cvec1, p_rel, c1, zbuf1, NTX);
        // agg0 = raw0@WV0 + raw1@WV1 (+ gated biases), in-place into edgebuf
        mfma_gemmV2<<<(NTX + 63) / 64, 256, 0, stream>>>(
            edgebuf, bufB, wt + (size_t)(c0*2 + 1) * 32768, wt + (size_t)(c1*2 + 1) * 32768,
            W0 + 32896, W1 + 32896, zbuf0, zbuf1, NTX);

        // r2 (dst=cust) and r3 (dst=merch): qt -> bufB regions, gather, V in-place
        for (int r = 2; r < 4; ++r) {
            int st = src_t[r], dt = dst_t[r];
            int ndt = (int)nsz[dt];
            int combo = l * 4 + r;
            const float* Wr = wc + (size_t)combo * WC_STRIDE;
            float* buf = aggT[dt];
            int grid = (ndt + 63) / 64;
            mfma_gemm<0, 1><<<grid, 256, 0, stream>>>(
                xs[dt], wt + (size_t)(combo*2) * 32768, Wr + 32768, buf, ndt,
                nullptr, nullptr, nullptr, Wr + 33024, Wr + 33152, cvec0);
            gather_agg<<<(ndt + 7) / 8, 256, 0, stream>>>(
                rowp[r], colix[r], buf, xs[st], cvec0, p_rel, combo, zbuf0, ndt);
            mfma_gemm<3, 0><<<grid, 256, 0, stream>>>(
                buf, wt + (size_t)(combo*2 + 1) * 32768, Wr + 32896, buf, ndt,
                nullptr, nullptr, zbuf0, nullptr, nullptr, nullptr);
        }

        // update: xs = relu(beta*(gelu(agg)@aw + ab) + (1-beta)*xs)
        for (int t = 0; t < 3; ++t)
            mfma_gemm<1, 0><<<(int)((nsz[t] + 63) / 64), 256, 0, stream>>>(
                aggT[t], wt + (size_t)(16 + l*3 + t) * 32768,
                ab + (size_t)(l*3 + t)*H, xs[t], (int)nsz[t],
                xs[t], skip + l*3 + t, nullptr, nullptr, nullptr, nullptr);
    }

    out_kernel<<<(NTX * 32 + 255) / 256, 256, 0, stream>>>(xs[0], out_w, out_b, (float*)d_out, NTX);
}

// Round 8
// 1142.663 us; speedup vs baseline: 3.5318x; 1.0820x over previous
//
#include <hip/hip_runtime.h>
#include <math.h>

#define H 128
#define NTX 150000
#define NCU 40000
#define NME 10000
#define NEDGE 150000
#define NLAY 2
#define WC_STRIDE 33280     // per (l,r): QWc@0, WVc@16384, qbc@32768, bvc@32896
#define WKC_STRIDE 16640    // per (l,r): WKc@0
#define BUF_FLOATS 19200000       // NTX*H (edgebuf and bufB each)
#define AGG2_OFF 5120000          // bufB offset for agg[2] region (after NCU*H)
#define SCAN_TILE 2048

typedef short s8v __attribute__((ext_vector_type(8)));
typedef float f32x4 __attribute__((ext_vector_type(4)));

__device__ __forceinline__ float gelu_exact(float x) {
    return 0.5f * x * (1.0f + erff(x * 0.70710678118654752f));
}
__device__ __forceinline__ unsigned short f2bf(float x) {   // RNE f32->bf16 bits
    unsigned u = __float_as_uint(x);
    return (unsigned short)((u + 0x7FFFu + ((u >> 16) & 1u)) >> 16);
}
__device__ __forceinline__ float bf2f(unsigned short b) {
    return __uint_as_float(((unsigned)b) << 16);
}

// ---------- fills ----------
__global__ __launch_bounds__(256) void fill_val(float* p, int n, float v) {
    int i = blockIdx.x * 256 + threadIdx.x;
    if (i < n) p[i] = v;
}
__global__ __launch_bounds__(256) void zero_int(int* p, int n) {
    int i = blockIdx.x * 256 + threadIdx.x;
    if (i < n) p[i] = 0;
}
__global__ __launch_bounds__(256) void copy_int(int* d, const int* s, int n) {
    int i = blockIdx.x * 256 + threadIdx.x;
    if (i < n) d[i] = s[i];
}

// ---------- CSR build ----------
__global__ __launch_bounds__(256) void count_deg(const int* __restrict__ dst,
    int* __restrict__ deg, int E)
{
    int e = blockIdx.x * 256 + threadIdx.x;
    if (e < E) atomicAdd(&deg[dst[e]], 1);
}
__global__ __launch_bounds__(256) void scan1(const int* __restrict__ deg,
    int* __restrict__ out, int* __restrict__ bsum, int n)
{
    __shared__ int ts[256];
    int tid = threadIdx.x;
    int base = blockIdx.x * SCAN_TILE + tid * 8;
    int v[8], pre[8], s = 0;
    #pragma unroll
    for (int j = 0; j < 8; ++j) {
        int idx = base + j;
        v[j] = (idx < n) ? deg[idx] : 0;
        pre[j] = s; s += v[j];
    }
    ts[tid] = s;
    __syncthreads();
    for (int off = 1; off < 256; off <<= 1) {
        int t = (tid >= off) ? ts[tid - off] : 0;
        __syncthreads();
        ts[tid] += t;
        __syncthreads();
    }
    int excl = ts[tid] - s;
    #pragma unroll
    for (int j = 0; j < 8; ++j)
        if (base + j < n) out[base + j] = excl + pre[j];
    if (tid == 255) bsum[blockIdx.x] = ts[255];
}
__global__ __launch_bounds__(64) void scan2(int* __restrict__ bsum, int nb) {
    if (threadIdx.x == 0 && blockIdx.x == 0) {
        int run = 0;
        for (int i = 0; i < nb; ++i) { int t = bsum[i]; bsum[i] = run; run += t; }
    }
}
__global__ __launch_bounds__(256) void scan3(int* __restrict__ out,
    const int* __restrict__ bsum, int n, int total)
{
    int base = blockIdx.x * SCAN_TILE;
    int add = bsum[blockIdx.x];
    for (int j = threadIdx.x; j < SCAN_TILE; j += 256) {
        int k = base + j;
        if (k < n) out[k] += add;
    }
    if (blockIdx.x == 0 && threadIdx.x == 0) out[n] = total;
}
__global__ __launch_bounds__(256) void fill_csr(const int* __restrict__ src,
    const int* __restrict__ dst, int* __restrict__ cursor, int* __restrict__ col, int E)
{
    int e = blockIdx.x * 256 + threadIdx.x;
    if (e >= E) return;
    int pos = atomicAdd(&cursor[dst[e]], 1);
    col[pos] = src[e];
}

// ---------- vectorized projection: Y = X(NxK) @ W(KxH) + b, 8 nodes/block ----------
template<int K>
__global__ __launch_bounds__(256) void proj_kernel(const float* __restrict__ X,
    const float* __restrict__ W, const float* __restrict__ B,
    float* __restrict__ Y, int N)
{
    __shared__ float Wl[K][128];
    __shared__ float Bl[128];
    int tid = threadIdx.x;
    for (int i = tid; i < K * 128; i += 256) Wl[i >> 7][i & 127] = W[i];
    if (tid < 128) Bl[tid] = B[tid];
    __syncthreads();
    int ng = tid >> 5, lane = tid & 31;
    int n = blockIdx.x * 8 + ng;
    if (n >= N) return;
    const float* xr = X + (size_t)n * K;
    float xa[K];
    #pragma unroll
    for (int k4 = 0; k4 < K / 4; ++k4)
        *(float4*)&xa[k4 * 4] = *(const float4*)(xr + k4 * 4);
    int c0 = lane * 4;
    float4 acc = *(const float4*)&Bl[c0];
    #pragma unroll
    for (int k = 0; k < K; ++k) {
        float4 w = *(const float4*)&Wl[k][c0];
        acc.x += xa[k] * w.x; acc.y += xa[k] * w.y;
        acc.z += xa[k] * w.z; acc.w += xa[k] * w.w;
    }
    *(float4*)(Y + (size_t)n * H + c0) = acc;
}

// ---------- gather rows ----------
__global__ __launch_bounds__(256) void gather_rows(const float* __restrict__ src,
    const int* __restrict__ ids, float* __restrict__ dstp, int N)
{
    int t = blockIdx.x * 256 + threadIdx.x;
    if (t >= N * 32) return;
    int n = t >> 5, c4 = t & 31;
    int sid = ids[n];
    ((float4*)dstp)[(size_t)n * 32 + c4] = ((const float4*)src)[(size_t)sid * 32 + c4];
}

// ---------- combine stage 1 (parallel, 64 blocks) ----------
__global__ __launch_bounds__(256) void combine1_par(const float* __restrict__ kw,
    const float* __restrict__ kb, const float* __restrict__ vw, const float* __restrict__ vb,
    const float* __restrict__ a_rel, const float* __restrict__ m_rel,
    float* __restrict__ wkc, float* __restrict__ wc)
{
    __shared__ float Rs[64][132];
    int b = blockIdx.x;
    int combo = b >> 3;
    int pass  = (b >> 2) & 1;
    int slice = b & 3;
    int l = combo >> 2, r = combo & 3;
    const int src_t[4] = {1, 2, 0, 0};
    int st = src_t[r];
    const float* Ap = (pass ? vw : kw) + (size_t)(l*3 + st) * H * H;
    const float* Rp = (pass ? m_rel : a_rel) + (size_t)combo * H * H;
    float* Out = pass ? (wc + (size_t)combo * WC_STRIDE + 16384)
                      : (wkc + (size_t)combo * WKC_STRIDE);

    int tid = threadIdx.x;
    int i = slice * 32 + (tid >> 3);
    int jb = tid & 7;
    float acc[16];
    #pragma unroll
    for (int j = 0; j < 16; ++j) acc[j] = 0.f;

    for (int half = 0; half < 2; ++half) {
        __syncthreads();
        for (int idx = tid; idx < 64 * 128; idx += 256)
            Rs[idx >> 7][idx & 127] = Rp[(half * 64 + (idx >> 7)) * H + (idx & 127)];
        __syncthreads();
        for (int k = 0; k < 64; ++k) {
            float a = Ap[i * H + half * 64 + k];
            #pragma unroll
            for (int j = 0; j < 16; ++j) acc[j] += a * Rs[k][jb + j * 8];
        }
    }
    #pragma unroll
    for (int j = 0; j < 16; ++j) Out[i * H + jb + j * 8] = acc[j];

    // bvc = vb @ m_rel  (cvec/bkc terms cancel in segment softmax -> not computed)
    if (pass == 0 && slice == 0 && tid < 128) {
        const float* Avb = vb + (size_t)(l*3 + st) * H;
        const float* Rv = m_rel + (size_t)combo * H * H;
        float* bvc = wc + (size_t)combo * WC_STRIDE + 32896;
        float s = 0.f;
        for (int k = 0; k < H; ++k) s += Avb[k] * Rv[k * H + tid];
        bvc[tid] = s;
    }
}

// ---------- combine stage 2 (parallel, 32 blocks): QWc = qw[dt] @ WKc^T ----------
__global__ __launch_bounds__(256) void combine2_par(const float* __restrict__ qw,
    const float* __restrict__ qb, const float* __restrict__ wkc, float* __restrict__ wc)
{
    __shared__ float BsT[64][133];
    int b = blockIdx.x;
    int combo = b >> 2;
    int slice = b & 3;
    int l = combo >> 2, r = combo & 3;
    const int dst_t[4] = {0, 0, 1, 2};
    int dt = dst_t[r];
    const float* Q  = qw + (size_t)(l*3 + dt) * H * H;
    const float* Qb = qb + (size_t)(l*3 + dt) * H;
    const float* WKc = wkc + (size_t)combo * WKC_STRIDE;
    float* QWc = wc + (size_t)combo * WC_STRIDE;

    int tid = threadIdx.x;
    int i = slice * 32 + (tid >> 3);
    int jb = tid & 7;
    float acc[16];
    #pragma unroll
    for (int j = 0; j < 16; ++j) acc[j] = 0.f;

    for (int half = 0; half < 2; ++half) {
        __syncthreads();
        for (int idx = tid; idx < 64 * 128; idx += 256) {
            int j = idx >> 6, k = idx & 63;
            BsT[k][j] = WKc[j * H + half * 64 + k];
        }
        __syncthreads();
        for (int k = 0; k < 64; ++k) {
            float a = Q[i * H + half * 64 + k];
            #pragma unroll
            for (int j = 0; j < 16; ++j) acc[j] += a * BsT[k][jb + j * 8];
        }
    }
    #pragma unroll
    for (int j = 0; j < 16; ++j) QWc[i * H + jb + j * 8] = acc[j];

    if (slice == 0 && tid < 128) {
        float* qbc = wc + (size_t)combo * WC_STRIDE + 32768;
        float s = 0.f;
        for (int k = 0; k < H; ++k) s += Qb[k] * WKc[tid * H + k];
        qbc[tid] = s;
    }
}

// ---------- weight prep: transpose + split f32 -> bf16 hi/lo, layout [j][k] ----------
__global__ __launch_bounds__(256) void wprep(const float* __restrict__ wc,
    const float* __restrict__ aw, unsigned short* __restrict__ wt)
{
    int b = blockIdx.x;
    const float* src = (b < 16)
        ? wc + (size_t)(b >> 1) * WC_STRIDE + ((b & 1) ? 16384 : 0)
        : aw + (size_t)(b - 16) * 16384;
    unsigned short* hi = wt + (size_t)b * 32768;
    unsigned short* lo = hi + 16384;
    for (int idx = threadIdx.x; idx < 16384; idx += 256) {
        int k = idx >> 7, j = idx & 127;
        float w = src[idx];
        unsigned short h = f2bf(w);
        hi[j * 128 + k] = h;
        lo[j * 128 + k] = f2bf(w - bf2f(h));
    }
}

// ---------- staging helper: f32 row tile -> split-bf16 LDS planes ----------
#define STAGE_TILE(SRC, GELU)                                               \
    _Pragma("unroll")                                                       \
    for (int i = 0; i < 8; ++i) {                                           \
        int u = tid + i * 256;                                              \
        int n = u >> 5, c4 = u & 31;                                        \
        int gn = nb + n;                                                    \
        float4 v = make_float4(0.f, 0.f, 0.f, 0.f);                         \
        if (gn < N) v = *(const float4*)((SRC) + (size_t)gn * H + c4 * 4);  \
        if (GELU) {                                                         \
            v.x = gelu_exact(v.x); v.y = gelu_exact(v.y);                   \
            v.z = gelu_exact(v.z); v.w = gelu_exact(v.w);                   \
        }                                                                   \
        ushort4 h, lo;                                                      \
        h.x = f2bf(v.x); lo.x = f2bf(v.x - bf2f(h.x));                      \
        h.y = f2bf(v.y); lo.y = f2bf(v.y - bf2f(h.y));                      \
        h.z = f2bf(v.z); lo.z = f2bf(v.z - bf2f(h.z));                      \
        h.w = f2bf(v.w); lo.w = f2bf(v.w - bf2f(h.w));                      \
        *(ushort4*)&lds[0][n][c4 * 4] = h;                                  \
        *(ushort4*)&lds[1][n][c4 * 4] = lo;                                 \
    }

#define LOAD_BFRAG(WT)                                                      \
    _Pragma("unroll")                                                       \
    for (int n = 0; n < 2; ++n) {                                           \
        int j = col0 + n * 16 + l15;                                        \
        _Pragma("unroll")                                                   \
        for (int kb = 0; kb < 4; ++kb) {                                    \
            bhi[n][kb] = *(const s8v*)((WT) + (size_t)j * 128 + kb * 32 + kg * 8);          \
            blo[n][kb] = *(const s8v*)((WT) + 16384 + (size_t)j * 128 + kb * 32 + kg * 8);  \
        }                                                                   \
    }

#define MFMA_PASS()                                                         \
    _Pragma("unroll")                                                       \
    for (int m = 0; m < 4; ++m) {                                           \
        int row = m * 16 + l15;                                             \
        _Pragma("unroll")                                                   \
        for (int kb = 0; kb < 4; ++kb) {                                    \
            s8v ah = *(const s8v*)&lds[0][row][kb * 32 + kg * 8];           \
            s8v al = *(const s8v*)&lds[1][row][kb * 32 + kg * 8];           \
            _Pragma("unroll")                                               \
            for (int n = 0; n < 2; ++n) {                                   \
                acc[m][n] = __builtin_amdgcn_mfma_f32_16x16x32_bf16(ah, bhi[n][kb], acc[m][n], 0, 0, 0); \
                acc[m][n] = __builtin_amdgcn_mfma_f32_16x16x32_bf16(al, bhi[n][kb], acc[m][n], 0, 0, 0); \
                acc[m][n] = __builtin_amdgcn_mfma_f32_16x16x32_bf16(ah, blo[n][kb], acc[m][n], 0, 0, 0); \
            }                                                               \
        }                                                                   \
    }

// ---------- MFMA split-bf16 GEMM (single weight set) ----------
// MODE 0: Y = X@W + B
// MODE 1: Y = relu(beta*(gelu(X)@W + B) + (1-beta)*Xold)
// MODE 3: Y = X@W + gate*B    (gate = zb[n]>0; X==Y in-place allowed)
template<int MODE>
__global__ __launch_bounds__(256) void mfma_gemm(const float* __restrict__ X,
    const unsigned short* __restrict__ Wt, const float* __restrict__ Bias,
    float* __restrict__ Y, int N, const float* __restrict__ Xold,
    const float* __restrict__ skipP, const float* __restrict__ zb)
{
    __shared__ unsigned short lds[2][64][136];
    int tid = threadIdx.x;
    int nb = blockIdx.x * 64;

    STAGE_TILE(X, MODE == 1)
    __syncthreads();

    int wid = tid >> 6, lane = tid & 63;
    int l15 = lane & 15, kg = lane >> 4;
    int col0 = wid * 32;

    s8v bhi[2][4], blo[2][4];
    LOAD_BFRAG(Wt)

    f32x4 acc[4][2];
    #pragma unroll
    for (int m = 0; m < 4; ++m)
        #pragma unroll
        for (int n = 0; n < 2; ++n)
            acc[m][n] = (f32x4){0.f, 0.f, 0.f, 0.f};

    MFMA_PASS()

    float beta = 0.f, omb = 0.f;
    if (MODE == 1) {
        float s = *skipP;
        beta = 1.f / (1.f + expf(-s));
        omb = 1.f - beta;
    }
    float bias0 = Bias[col0 + l15];
    float bias1 = Bias[col0 + 16 + l15];

    #pragma unroll
    for (int m = 0; m < 4; ++m) {
        #pragma unroll
        for (int r = 0; r < 4; ++r) {
            int grow = nb + m * 16 + kg * 4 + r;
            if (grow < N) {
                float gate = 1.f;
                if (MODE == 3) gate = (zb[grow] > 0.f) ? 1.f : 0.f;
                #pragma unroll
                for (int n = 0; n < 2; ++n) {
                    int col = col0 + n * 16 + l15;
                    float val = acc[m][n][r];
                    float bs = n ? bias1 : bias0;
                    size_t yi = (size_t)grow * H + col;
                    if (MODE == 0) {
                        Y[yi] = val + bs;
                    } else if (MODE == 3) {
                        Y[yi] = val + gate * bs;
                    } else {
                        float o = val + bs;
                        float xo = Xold[yi];
                        Y[yi] = fmaxf(beta * o + omb * xo, 0.f);
                    }
                }
            }
        }
    }
}

// ---------- fused dual qt GEMM: Y0 = X@W0 + b0, Y1 = X@W1 + b1 ----------
__global__ __launch_bounds__(256) void mfma_gemm2q(const float* __restrict__ X,
    const unsigned short* __restrict__ Wt0, const unsigned short* __restrict__ Wt1,
    const float* __restrict__ b0, const float* __restrict__ b1,
    float* __restrict__ Y0, float* __restrict__ Y1, int N)
{
    __shared__ unsigned short lds[2][64][136];
    int tid = threadIdx.x;
    int nb = blockIdx.x * 64;

    STAGE_TILE(X, 0)
    __syncthreads();

    int wid = tid >> 6, lane = tid & 63;
    int l15 = lane & 15, kg = lane >> 4;
    int col0 = wid * 32;

    #pragma unroll
    for (int set = 0; set < 2; ++set) {
        const unsigned short* Wt = set ? Wt1 : Wt0;
        const float* Bias = set ? b1 : b0;
        float* Y = set ? Y1 : Y0;

        s8v bhi[2][4], blo[2][4];
        LOAD_BFRAG(Wt)

        f32x4 acc[4][2];
        #pragma unroll
        for (int m = 0; m < 4; ++m)
            #pragma unroll
            for (int n = 0; n < 2; ++n)
                acc[m][n] = (f32x4){0.f, 0.f, 0.f, 0.f};

        MFMA_PASS()

        float bias0 = Bias[col0 + l15];
        float bias1 = Bias[col0 + 16 + l15];
        #pragma unroll
        for (int m = 0; m < 4; ++m) {
            #pragma unroll
            for (int r = 0; r < 4; ++r) {
                int grow = nb + m * 16 + kg * 4 + r;
                if (grow < N) {
                    #pragma unroll
                    for (int n = 0; n < 2; ++n) {
                        int col = col0 + n * 16 + l15;
                        Y[(size_t)grow * H + col] = acc[m][n][r] + (n ? bias1 : bias0);
                    }
                }
            }
        }
    }
}

// ---------- fused K=256 V-GEMM: A0 <- A0@W0 + A1@W1 + gate0*b0 + gate1*b1 (in-place) ----------
__global__ __launch_bounds__(256) void mfma_gemmV2(float* __restrict__ A0,
    const float* __restrict__ A1,
    const unsigned short* __restrict__ Wt0, const unsigned short* __restrict__ Wt1,
    const float* __restrict__ bv0, const float* __restrict__ bv1,
    const float* __restrict__ z0, const float* __restrict__ z1, int N)
{
    __shared__ unsigned short lds[2][64][136];
    int tid = threadIdx.x;
    int nb = blockIdx.x * 64;
    int wid = tid >> 6, lane = tid & 63;
    int l15 = lane & 15, kg = lane >> 4;
    int col0 = wid * 32;

    f32x4 acc[4][2];
    #pragma unroll
    for (int m = 0; m < 4; ++m)
        #pragma unroll
        for (int n = 0; n < 2; ++n)
            acc[m][n] = (f32x4){0.f, 0.f, 0.f, 0.f};

    #pragma unroll
    for (int half = 0; half < 2; ++half) {
        const float* A = half ? A1 : A0;
        const unsigned short* Wt = half ? Wt1 : Wt0;
        if (half) __syncthreads();   // prior LDS reads done before restage
        STAGE_TILE(A, 0)
        __syncthreads();
        s8v bhi[2][4], blo[2][4];
        LOAD_BFRAG(Wt)
        MFMA_PASS()
    }

    float b00 = bv0[col0 + l15],  b01 = bv0[col0 + 16 + l15];
    float b10 = bv1[col0 + l15],  b11 = bv1[col0 + 16 + l15];

    #pragma unroll
    for (int m = 0; m < 4; ++m) {
        #pragma unroll
        for (int r = 0; r < 4; ++r) {
            int grow = nb + m * 16 + kg * 4 + r;
            if (grow < N) {
                float g0 = (z0[grow] > 0.f) ? 1.f : 0.f;
                float g1 = (z1[grow] > 0.f) ? 1.f : 0.f;
                #pragma unroll
                for (int n = 0; n < 2; ++n) {
                    int col = col0 + n * 16 + l15;
                    float bs = n ? (g0 * b01 + g1 * b11) : (g0 * b00 + g1 * b10);
                    A0[(size_t)grow * H + col] = acc[m][n][r] + bs;
                }
            }
        }
    }
}

// ---------- fused edge phase: per dst node, single pass over CSR ----------
__global__ __launch_bounds__(256) void gather_agg(const int* __restrict__ row_ptr,
    const int* __restrict__ col_idx, float* __restrict__ qtraw,
    const float* __restrict__ xsrc, const float* __restrict__ prel, int ridx,
    float* __restrict__ zout, int ndt)
{
    int g = blockIdx.x * 8 + (threadIdx.x >> 5);
    int lane = threadIdx.x & 31;
    if (g >= ndt) return;
    float4 qv = *(const float4*)(qtraw + (size_t)g * H + lane * 4);
    float scale = prel[ridx] * 0.08838834764831843f;   // 1/sqrt(128)
    int beg = row_ptr[g], end = row_ptr[g + 1];
    float4 acc = make_float4(0.f, 0.f, 0.f, 0.f);
    float z = 0.f;
    for (int i = beg; i < end; ++i) {
        int s = col_idx[i];
        float4 xv = *(const float4*)(xsrc + (size_t)s * H + lane * 4);
        float p = qv.x*xv.x + qv.y*xv.y + qv.z*xv.z + qv.w*xv.w;
        #pragma unroll
        for (int m = 16; m >= 1; m >>= 1) p += __shfl_xor(p, m);
        float ev = expf(p * scale);
        z += ev;
        acc.x += ev * xv.x; acc.y += ev * xv.y;
        acc.z += ev * xv.z; acc.w += ev * xv.w;
    }
    float inv = 1.f / (z + 1e-16f);
    float4 r = make_float4(acc.x * inv, acc.y * inv, acc.z * inv, acc.w * inv);
    *(float4*)(qtraw + (size_t)g * H + lane * 4) = r;
    if (lane == 0) zout[g] = z;
}

// ---------- output head ----------
__global__ __launch_bounds__(256) void out_kernel(const float* __restrict__ X,
    const float* __restrict__ Wo, const float* __restrict__ bo,
    float* __restrict__ out, int N)
{
    int t = blockIdx.x * 256 + threadIdx.x;
    int n = t >> 5, lane = t & 31;
    if (n >= N) return;
    float4 xv = *(const float4*)(X + (size_t)n * H + lane * 4);
    float xa[4]; *(float4*)xa = xv;
    float p0 = 0.f, p1 = 0.f;
    #pragma unroll
    for (int j = 0; j < 4; ++j) {
        p0 += xa[j] * Wo[(lane*4 + j)*2 + 0];
        p1 += xa[j] * Wo[(lane*4 + j)*2 + 1];
    }
    #pragma unroll
    for (int m = 16; m >= 1; m >>= 1) { p0 += __shfl_xor(p0, m); p1 += __shfl_xor(p1, m); }
    if (lane == 0) {
        out[(size_t)n*2 + 0] = p0 + bo[0];
        out[(size_t)n*2 + 1] = p1 + bo[1];
    }
}

extern "C" void kernel_launch(void* const* d_in, const int* in_sizes, int n_in,
                              void* d_out, int out_size, void* d_ws, size_t ws_size,
                              hipStream_t stream)
{
    const float* x_tx      = (const float*)d_in[0];
    const float* x_cust    = (const float*)d_in[1];
    const int*   merch_ids = (const int*)d_in[2];
    const int*   e_ct_src  = (const int*)d_in[3];
    const int*   e_ct_dst  = (const int*)d_in[4];
    const int*   e_mt_src  = (const int*)d_in[5];
    const int*   e_mt_dst  = (const int*)d_in[6];
    const float* proj_tx_w   = (const float*)d_in[7];
    const float* proj_tx_b   = (const float*)d_in[8];
    const float* proj_cust_w = (const float*)d_in[9];
    const float* proj_cust_b = (const float*)d_in[10];
    const float* merch_emb   = (const float*)d_in[11];
    const float* kw = (const float*)d_in[12];
    const float* kb = (const float*)d_in[13];
    const float* qw = (const float*)d_in[14];
    const float* qb = (const float*)d_in[15];
    const float* vw = (const float*)d_in[16];
    const float* vb = (const float*)d_in[17];
    const float* aw = (const float*)d_in[18];
    const float* ab = (const float*)d_in[19];
    const float* skip  = (const float*)d_in[20];
    const float* a_rel = (const float*)d_in[21];
    const float* m_rel = (const float*)d_in[22];
    const float* p_rel = (const float*)d_in[23];
    const float* out_w = (const float*)d_in[24];
    const float* out_b = (const float*)d_in[25];
    (void)in_sizes; (void)n_in;

    const size_t nsz[3] = {NTX, NCU, NME};

    // workspace layout — ~265 MB of 268.4 MB (256 MiB) budget
    float* ws = (float*)d_ws;
    size_t off = 0;
    float* xs[3];  for (int t = 0; t < 3; ++t) { xs[t] = ws + off; off += nsz[t]*H; }
    float* bufB    = ws + off; off += BUF_FLOATS;   // qt_r1/raw_r1; later agg1 @0, agg2 @AGG2_OFF
    float* edgebuf = ws + off; off += BUF_FLOATS;   // qt_r0/raw_r0 -> agg0 (in-place V2)
    float* zbuf0 = ws + off; off += NTX;
    float* zbuf1 = ws + off; off += NTX;
    float* wc   = ws + off; off += 8 * WC_STRIDE;
    float* wkc  = ws + off; off += 8 * WKC_STRIDE;
    int* ibase = (int*)(ws + off);
    const int rp_size[4] = {NTX + 1, NTX + 1, NCU + 1, NME + 1};
    int* rowp[4]; size_t ioff = 0;
    for (int r = 0; r < 4; ++r) { rowp[r] = ibase + ioff; ioff += rp_size[r]; }
    int* colix[4];
    for (int r = 0; r < 4; ++r) { colix[r] = ibase + ioff; ioff += NEDGE; }
    int* cursor = ibase + ioff; ioff += NTX;
    int* bsum   = ibase + ioff; ioff += 256;
    unsigned short* wt = (unsigned short*)(ibase + ioff);
    size_t needed_bytes = off * sizeof(float) + ioff * sizeof(int)
                        + (size_t)22 * 32768 * sizeof(unsigned short);

    if (ws_size < needed_bytes) {
        fill_val<<<(out_size + 255) / 256, 256, 0, stream>>>(
            (float*)d_out, out_size, (float)(ws_size >> 20));
        return;
    }

    const int src_t[4] = {1, 2, 0, 0};
    const int dst_t[4] = {0, 0, 1, 2};
    const int* esrc[4] = {e_ct_src, e_mt_src, e_ct_dst, e_mt_dst};
    const int* edst[4] = {e_ct_dst, e_mt_dst, e_ct_src, e_mt_src};

    // ---- build CSR per relation (edges constant across layers) ----
    const int egrid256 = (NEDGE + 255) / 256;
    for (int r = 0; r < 4; ++r) {
        int ndt = (int)nsz[dst_t[r]];
        int nb = (ndt + SCAN_TILE - 1) / SCAN_TILE;
        zero_int<<<(ndt + 255) / 256, 256, 0, stream>>>(cursor, ndt);
        count_deg<<<egrid256, 256, 0, stream>>>(edst[r], cursor, NEDGE);
        scan1<<<nb, 256, 0, stream>>>(cursor, rowp[r], bsum, ndt);
        scan2<<<1, 64, 0, stream>>>(bsum, nb);
        scan3<<<nb, 256, 0, stream>>>(rowp[r], bsum, ndt, NEDGE);
        copy_int<<<(ndt + 255) / 256, 256, 0, stream>>>(cursor, rowp[r], ndt);
        fill_csr<<<egrid256, 256, 0, stream>>>(esrc[r], edst[r], cursor, colix[r], NEDGE);
    }

    // precombine weights, then bf16 hi/lo transposed planes
    combine1_par<<<64, 256, 0, stream>>>(kw, kb, vw, vb, a_rel, m_rel, wkc, wc);
    combine2_par<<<32, 256, 0, stream>>>(qw, qb, wkc, wc);
    wprep<<<22, 256, 0, stream>>>(wc, aw, wt);

    // input projections
    proj_kernel<16><<<(NTX + 7) / 8, 256, 0, stream>>>(x_tx, proj_tx_w, proj_tx_b, xs[0], NTX);
    proj_kernel<32><<<(NCU + 7) / 8, 256, 0, stream>>>(x_cust, proj_cust_w, proj_cust_b, xs[1], NCU);
    gather_rows<<<(NME * 32 + 255) / 256, 256, 0, stream>>>(merch_emb, merch_ids, xs[2], NME);

    float* aggT[3] = { edgebuf, bufB, bufB + AGG2_OFF };

    for (int l = 0; l < NLAY; ++l) {
        int c0 = l * 4 + 0, c1 = l * 4 + 1;
        const float* W0 = wc + (size_t)c0 * WC_STRIDE;
        const float* W1 = wc + (size_t)c1 * WC_STRIDE;

        // fused r0+r1 qt (dt = tx for both): X read once
        mfma_gemm2q<<<(NTX + 63) / 64, 256, 0, stream>>>(
            xs[0], wt + (size_t)(c0*2) * 32768, wt + (size_t)(c1*2) * 32768,
            W0 + 32768, W1 + 32768, edgebuf, bufB, NTX);
        gather_agg<<<(NTX + 7) / 8, 256, 0, stream>>>(
            rowp[0], colix[0], edgebuf, xs[1], p_rel, c0, zbuf0, NTX);
        gather_agg<<<(NTX + 7) / 8, 256, 0, stream>>>(
            rowp[1], colix[1], bufB, xs[2], p_rel, c1, zbuf1, NTX);
        // agg0 = raw0@WV0 + raw1@WV1 (+ gated biases), in-place into edgebuf
        mfma_gemmV2<<<(NTX + 63) / 64, 256, 0, stream>>>(
            edgebuf, bufB, wt + (size_t)(c0*2 + 1) * 32768, wt + (size_t)(c1*2 + 1) * 32768,
            W0 + 32896, W1 + 32896, zbuf0, zbuf1, NTX);

        // r2 (dst=cust) and r3 (dst=merch): qt -> bufB regions, gather, V in-place
        for (int r = 2; r < 4; ++r) {
            int st = src_t[r], dt = dst_t[r];
            int ndt = (int)nsz[dt];
            int combo = l * 4 + r;
            const float* Wr = wc + (size_t)combo * WC_STRIDE;
            float* buf = aggT[dt];
            int grid = (ndt + 63) / 64;
            mfma_gemm<0><<<grid, 256, 0, stream>>>(
                xs[dt], wt + (size_t)(combo*2) * 32768, Wr + 32768, buf, ndt,
                nullptr, nullptr, nullptr);
            gather_agg<<<(ndt + 7) / 8, 256, 0, stream>>>(
                rowp[r], colix[r], buf, xs[st], p_rel, combo, zbuf0, ndt);
            mfma_gemm<3><<<grid, 256, 0, stream>>>(
                buf, wt + (size_t)(combo*2 + 1) * 32768, Wr + 32896, buf, ndt,
                nullptr, nullptr, zbuf0);
        }

        // update: xs = relu(beta*(gelu(agg)@aw + ab) + (1-beta)*xs)
        for (int t = 0; t < 3; ++t)
            mfma_gemm<1><<<(int)((nsz[t] + 63) / 64), 256, 0, stream>>>(
                aggT[t], wt + (size_t)(16 + l*3 + t) * 32768,
                ab + (size_t)(l*3 + t)*H, xs[t], (int)nsz[t],
                xs[t], skip + l*3 + t, nullptr);
    }

    out_kernel<<<(NTX * 32 + 255) / 256, 256, 0, stream>>>(xs[0], out_w, out_b, (float*)d_out, NTX);
}